// Round 1
// baseline (436.293 us; speedup 1.0000x reference)
//
#include <hip/hip_runtime.h>
#include <math.h>

#define N_NODES 20000
#define MP      20032          // M padded to 64
#define N_EDGES 320000
#define F_IN    518
#define HIDDEN  256
#define DIM     128
#define NH      4

typedef __attribute__((ext_vector_type(8))) short bf16x8;
typedef __attribute__((ext_vector_type(4))) float f32x4;
typedef unsigned short ushort_t;

__device__ __forceinline__ float lrelu02(float x) { return x > 0.f ? x : 0.2f * x; }

__device__ __forceinline__ void gl_lds16(const void* g, void* l) {
    __builtin_amdgcn_global_load_lds(
        (const __attribute__((address_space(1))) unsigned int*)g,
        (__attribute__((address_space(3))) unsigned int*)l, 16, 0, 0);
}

__device__ __forceinline__ unsigned int hi16(float v) { return __float_as_uint(v) >> 16; }
__device__ __forceinline__ unsigned int lo16(float v) {
    unsigned int h = __float_as_uint(v) & 0xFFFF0000u;
    return __float_as_uint(v - __uint_as_float(h)) >> 16;
}
// round-to-nearest-even bf16
__device__ __forceinline__ unsigned int rnd16(float v) {
    unsigned int u = __float_as_uint(v);
    return (u + 0x7FFFu + ((u >> 16) & 1u)) >> 16;
}
__device__ __forceinline__ float bfl(unsigned int u) { return __uint_as_float(u << 16); }
__device__ __forceinline__ float bfh(unsigned int u) { return __uint_as_float(u & 0xFFFF0000u); }

// ====== split-bf16 MFMA GEMM, operands pre-split, k-chunk-major ======
__global__ __launch_bounds__(256, 4) void gemm_mfma_v2(
    const ushort_t* __restrict__ Ah, const ushort_t* __restrict__ Al,
    const ushort_t* __restrict__ Bh, const ushort_t* __restrict__ Bl,
    const float* __restrict__ bias,
    int M, int K8, int N, int act,
    float* __restrict__ Cf,                                      // fp32 [M][N]
    ushort_t* __restrict__ Ch, ushort_t* __restrict__ Cl,        // split A-layout
    ushort_t* __restrict__ Cb,                                   // plain bf16 [M][N]
    ushort_t* __restrict__ Ca)                                   // plain bf16 A-layout
{
    __shared__ __align__(16) ushort_t lds[12288];
    const int tid = threadIdx.x;
    const int w = tid >> 6, lane = tid & 63;
    const int row0 = blockIdx.y * 64, col0 = blockIdx.x * 128;
    const int nkb = K8 >> 2;
    const int m16 = lane & 15, q = lane >> 4;
    const bool use_al = (Al != nullptr);

    f32x4 acc[4][2] = {};

    for (int kb = 0; kb < nkb; ++kb) {
        const size_t kc = (size_t)(kb * 4 + w);
        const size_t aoff = (kc * MP + row0) * 8 + lane * 8;
        const size_t boff = (kc * N + col0) * 8 + lane * 8;
        gl_lds16(Ah + aoff, &lds[w * 512]);
        if (use_al) gl_lds16(Al + aoff, &lds[2048 + w * 512]);
        gl_lds16(Bh + boff,       &lds[4096 + w * 1024]);
        gl_lds16(Bh + boff + 512, &lds[4096 + w * 1024 + 512]);
        gl_lds16(Bl + boff,       &lds[8192 + w * 1024]);
        gl_lds16(Bl + boff + 512, &lds[8192 + w * 1024 + 512]);
        __syncthreads();

        bf16x8 fah[4], fal[4], fbh[2], fbl[2];
        const int fa = q * 512 + m16 * 8;
        #pragma unroll
        for (int mi = 0; mi < 4; ++mi) {
            fah[mi] = *(const bf16x8*)&lds[fa + mi * 128];
            if (use_al) fal[mi] = *(const bf16x8*)&lds[2048 + fa + mi * 128];
        }
        const int fb = q * 1024 + (w * 32 + m16) * 8;
        #pragma unroll
        for (int ni = 0; ni < 2; ++ni) {
            fbh[ni] = *(const bf16x8*)&lds[4096 + fb + ni * 128];
            fbl[ni] = *(const bf16x8*)&lds[8192 + fb + ni * 128];
        }
        #pragma unroll
        for (int mi = 0; mi < 4; ++mi)
            #pragma unroll
            for (int ni = 0; ni < 2; ++ni) {
                acc[mi][ni] = __builtin_amdgcn_mfma_f32_16x16x32_bf16(fah[mi], fbh[ni], acc[mi][ni], 0, 0, 0);
                acc[mi][ni] = __builtin_amdgcn_mfma_f32_16x16x32_bf16(fah[mi], fbl[ni], acc[mi][ni], 0, 0, 0);
            }
        if (use_al) {
            #pragma unroll
            for (int mi = 0; mi < 4; ++mi)
                #pragma unroll
                for (int ni = 0; ni < 2; ++ni)
                    acc[mi][ni] = __builtin_amdgcn_mfma_f32_16x16x32_bf16(fal[mi], fbh[ni], acc[mi][ni], 0, 0, 0);
        }
        __syncthreads();
    }

    // epilogue: C/D row=(lane>>4)*4+reg, col=lane&15
    #pragma unroll
    for (int ni = 0; ni < 2; ++ni) {
        const int col = col0 + w * 32 + ni * 16 + m16;
        const float bb = bias ? bias[col] : 0.f;
        #pragma unroll
        for (int mi = 0; mi < 4; ++mi) {
            #pragma unroll
            for (int r = 0; r < 4; ++r) {
                const int row = row0 + mi * 16 + q * 4 + r;
                if (row < M) {
                    float v = acc[mi][ni][r] + bb;
                    if (act) v = fmaxf(v, 0.f);
                    if (Cf) Cf[(size_t)row * N + col] = v;
                    if (Cb) Cb[(size_t)row * N + col] = (ushort_t)rnd16(v);
                    const size_t p = (((size_t)(col >> 3)) * MP + row) * 8 + (col & 7);
                    if (Ch) { Ch[p] = (ushort_t)hi16(v); Cl[p] = (ushort_t)lo16(v); }
                    if (Ca) Ca[p] = (ushort_t)rnd16(v);
                }
            }
        }
    }
}

// ---- x fp32 [N_NODES][F_IN] -> xh/xl bf16 [K8][MP][8], coalesced via LDS tile ----
__global__ __launch_bounds__(256) void conv_a_t_kernel(
    const float* __restrict__ x, ushort_t* __restrict__ xh, ushort_t* __restrict__ xl)
{
    __shared__ float tile[64][68];
    const int tid = threadIdx.x;
    const int r0 = blockIdx.x * 64;
    const int c0 = blockIdx.y * 64;

    #pragma unroll
    for (int it = 0; it < 4; ++it) {
        const int r = (tid >> 4) + it * 16;
        const int c = (tid & 15) * 4;
        const int gr = r0 + r, gc = c0 + c;
        float4 v = {0.f, 0.f, 0.f, 0.f};
        if (gr < N_NODES) {
            if (gc + 3 < F_IN) {
                v = *(const float4*)(x + (size_t)gr * F_IN + gc);
            } else {
                float tmp[4] = {0.f, 0.f, 0.f, 0.f};
                #pragma unroll
                for (int u = 0; u < 4; ++u)
                    if (gc + u < F_IN) tmp[u] = x[(size_t)gr * F_IN + gc + u];
                v.x = tmp[0]; v.y = tmp[1]; v.z = tmp[2]; v.w = tmp[3];
            }
        }
        tile[r][c] = v.x; tile[r][c+1] = v.y; tile[r][c+2] = v.z; tile[r][c+3] = v.w;
    }
    __syncthreads();

    const int k8l = tid >> 5;
    const int k8 = (c0 >> 3) + k8l;
    if (k8 >= 68) return;
    const int rr = (tid & 31) * 2;
    #pragma unroll
    for (int u = 0; u < 2; ++u) {
        const int r = rr + u;
        unsigned int hp[4], lp[4];
        #pragma unroll
        for (int i = 0; i < 4; ++i) {
            const float v0 = tile[r][k8l * 8 + 2 * i];
            const float v1 = tile[r][k8l * 8 + 2 * i + 1];
            hp[i] = (hi16(v1) << 16) | hi16(v0);
            lp[i] = (lo16(v1) << 16) | lo16(v0);
        }
        const size_t p = ((size_t)k8 * MP + r0 + r) * 8;
        *(uint4*)(xh + p) = make_uint4(hp[0], hp[1], hp[2], hp[3]);
        *(uint4*)(xl + p) = make_uint4(lp[0], lp[1], lp[2], lp[3]);
    }
}

// ---- all 4 weights fp32 -> bf16 hi/lo [K8][N][8] in ONE launch ----
#define W1_T (68 * 256 * 8)
#define W2_T (32 * 128 * 8)
#define L_T  (16 * 512 * 8)
__global__ __launch_bounds__(256) void conv_w_all_kernel(
    const float* __restrict__ w1, const float* __restrict__ w2,
    const float* __restrict__ l0, const float* __restrict__ l1,
    ushort_t* __restrict__ w1h, ushort_t* __restrict__ w1l,
    ushort_t* __restrict__ w2h, ushort_t* __restrict__ w2l,
    ushort_t* __restrict__ l0h, ushort_t* __restrict__ l0l,
    ushort_t* __restrict__ l1h, ushort_t* __restrict__ l1l)
{
    int idx = blockIdx.x * 256 + threadIdx.x;
    const float* w; ushort_t *bh, *bl; int K, N, local;
    if (idx < W1_T) { w = w1; bh = w1h; bl = w1l; K = F_IN; N = HIDDEN; local = idx; }
    else if (idx < W1_T + W2_T) { w = w2; bh = w2h; bl = w2l; K = HIDDEN; N = DIM; local = idx - W1_T; }
    else if (idx < W1_T + W2_T + L_T) { w = l0; bh = l0h; bl = l0l; K = DIM; N = 512; local = idx - W1_T - W2_T; }
    else if (idx < W1_T + W2_T + 2 * L_T) { w = l1; bh = l1h; bl = l1l; K = DIM; N = 512; local = idx - W1_T - W2_T - L_T; }
    else return;
    const int j = local & 7;
    const int rem = local >> 3;
    const int n = rem % N;
    const int k = (rem / N) * 8 + j;
    const float v = (k < K) ? w[(size_t)k * N + n] : 0.f;
    bh[local] = (ushort_t)hi16(v);
    bl[local] = (ushort_t)lo16(v);
}

// ---- wa for BOTH layers in one launch ----
__global__ __launch_bounds__(256) void wa2_kernel(
    const float* __restrict__ lin0, const float* __restrict__ lin1,
    const float* __restrict__ atts0, const float* __restrict__ attd0,
    const float* __restrict__ atts1, const float* __restrict__ attd1,
    float* __restrict__ wa_s0, float* __restrict__ wa_d0,
    float* __restrict__ wa_s1, float* __restrict__ wa_d1)
{
    const int wrk = blockIdx.x * 256 + threadIdx.x;
    if (wrk >= 2048) return;
    const int L = wrk >> 10;
    const int sd = (wrk >> 9) & 1;
    const int p = wrk & 511;
    const int h = p >> 7, d = p & 127;
    const float* lin = L ? lin1 : lin0;
    const float* av = L ? (sd ? attd1 : atts1) : (sd ? attd0 : atts0);
    float* out = L ? (sd ? wa_d1 : wa_s1) : (sd ? wa_d0 : wa_s0);
    const float* lp = lin + (size_t)d * (NH * DIM) + h * DIM;
    const float* ap = av + h * DIM;
    float acc = 0.f;
    #pragma unroll 8
    for (int i = 0; i < DIM; ++i) acc += lp[i] * ap[i];
    out[h * DIM + d] = acc;
}

// ---- a_s[n,h], a_d[n,h] from xbuf (fp32 [N][128]) ----
__global__ __launch_bounds__(256) void as_ad_kernel(
    const float* __restrict__ xb, const float* __restrict__ wa_s,
    const float* __restrict__ wa_d, float* __restrict__ a_s, float* __restrict__ a_d)
{
    const int gw = blockIdx.x * 4 + (threadIdx.x >> 6);
    const int lane = threadIdx.x & 63;
    if (gw >= N_NODES * NH) return;
    const int n = gw >> 2, h = gw & 3;
    const float* hp = xb + (size_t)n * DIM;
    float2 hv = *(const float2*)(hp + lane * 2);
    float2 sv = *(const float2*)(wa_s + h * DIM + lane * 2);
    float2 dv = *(const float2*)(wa_d + h * DIM + lane * 2);
    float s = hv.x * sv.x + hv.y * sv.y;
    float d = hv.x * dv.x + hv.y * dv.y;
    #pragma unroll
    for (int off = 32; off > 0; off >>= 1) {
        s += __shfl_down(s, off);
        d += __shfl_down(d, off);
    }
    if (lane == 0) { a_s[n * 4 + h] = s; a_d[n * 4 + h] = d; }
}

// ---- rel attention tables for BOTH layers: blockIdx.x = layer ----
__global__ __launch_bounds__(128) void rel_table2_kernel(
    const float* __restrict__ rel_emb,
    const float* __restrict__ line0, const float* __restrict__ atte0,
    const float* __restrict__ line1, const float* __restrict__ atte1,
    float* __restrict__ table)          // [2][128]
{
    __shared__ float we[32][NH];
    const int L = blockIdx.x;
    const float* line = L ? line1 : line0;
    const float* atte = L ? atte1 : atte0;
    float* tab = table + L * 128;
    const int tid = threadIdx.x;
    const int k = tid >> 2, h = tid & 3;
    float acc = 0.f;
    for (int d = 0; d < DIM; ++d)
        acc += line[(size_t)k * (NH * DIM) + h * DIM + d] * atte[h * DIM + d];
    we[k][h] = acc;
    __syncthreads();
    if (tid < 26 * NH) {
        int r = tid >> 2, hh = tid & 3;
        float t = 0.f;
        for (int kk = 0; kk < 32; ++kk) t += rel_emb[r * 32 + kk] * we[kk][hh];
        tab[r * 4 + hh] = t;
    }
}

// ================= CSR build =================
__global__ __launch_bounds__(256) void hist_kernel(
    const int* __restrict__ dst, int* __restrict__ cnt)
{
    const int e = blockIdx.x * blockDim.x + threadIdx.x;
    if (e >= N_EDGES) return;
    atomicAdd(&cnt[dst[e]], 1);
}

__global__ __launch_bounds__(1024) void scan_kernel(
    const int* __restrict__ cnt, int* __restrict__ ptr, int* __restrict__ ptr_copy)
{
    __shared__ int tsum[1024];
    const int tid = threadIdx.x;
    const int CH = 20;
    const int base = tid * CH;
    int s = 0;
    #pragma unroll
    for (int i = 0; i < CH; ++i) {
        int idx = base + i;
        if (idx < N_NODES) s += cnt[idx];
    }
    tsum[tid] = s;
    __syncthreads();
    for (int off = 1; off < 1024; off <<= 1) {
        int v = (tid >= off) ? tsum[tid - off] : 0;
        __syncthreads();
        tsum[tid] += v;
        __syncthreads();
    }
    int run = (tid == 0) ? 0 : tsum[tid - 1];
    #pragma unroll
    for (int i = 0; i < CH; ++i) {
        int idx = base + i;
        if (idx < N_NODES) {
            ptr[idx] = run;
            ptr_copy[idx] = run;
            run += cnt[idx];
        }
    }
    if (tid == 0) ptr[N_NODES] = N_EDGES;
}

__global__ __launch_bounds__(256) void scatter_kernel(
    const int* __restrict__ src, const int* __restrict__ dst, const int* __restrict__ etype,
    int* __restrict__ ptr_copy, int2* __restrict__ se, int* __restrict__ pose)
{
    const int e = blockIdx.x * blockDim.x + threadIdx.x;
    if (e >= N_EDGES) return;
    const int d = dst[e];
    const int pos = atomicAdd(&ptr_copy[d], 1);
    se[pos] = make_int2(src[e], etype[e]);
    pose[e] = pos;
}

// ======== per-edge softmax numerator p[pos][h] + per-node self-loop p ========
// Blocks [0, N_EDGES/256): one thread per edge, original order, write at CSR pos.
// Blocks [N_EDGES/256, ...): one thread per node, self-loop p from mean table val.
#define EP_EBLK (N_EDGES / 256)
__global__ __launch_bounds__(256) void edge_self_p_kernel(
    const int* __restrict__ src, const int* __restrict__ dst, const int* __restrict__ etype,
    const int* __restrict__ pose, const int* __restrict__ ptr, const int2* __restrict__ se,
    const float* __restrict__ a_s, const float* __restrict__ a_d,
    const float* __restrict__ table, float* __restrict__ p4, float* __restrict__ sp)
{
    const int b = blockIdx.x;
    if (b < EP_EBLK) {
        const int e = b * 256 + threadIdx.x;
        const int s = src[e], d = dst[e], et = etype[e];
        const float4 as = *(const float4*)(a_s + s * 4);
        const float4 ad = *(const float4*)(a_d + d * 4);
        const float4 t  = *(const float4*)(table + et * 4);
        float4 o;
        o.x = __expf(lrelu02(as.x + ad.x + t.x));
        o.y = __expf(lrelu02(as.y + ad.y + t.y));
        o.z = __expf(lrelu02(as.z + ad.z + t.z));
        o.w = __expf(lrelu02(as.w + ad.w + t.w));
        *(float4*)(p4 + (size_t)pose[e] * 4) = o;
    } else {
        const int n = (b - EP_EBLK) * 256 + threadIdx.x;
        if (n >= N_NODES) return;
        const int beg = ptr[n], end = ptr[n + 1];
        float t0 = 0.f, t1 = 0.f, t2 = 0.f, t3 = 0.f;
        for (int j = beg; j < end; ++j) {
            const float4 t = *(const float4*)(table + se[j].y * 4);
            t0 += t.x; t1 += t.y; t2 += t.z; t3 += t.w;
        }
        const float inv = 1.0f / fmaxf((float)(end - beg), 1.0f);
        const float4 as = *(const float4*)(a_s + n * 4);
        const float4 ad = *(const float4*)(a_d + n * 4);
        float4 o;
        o.x = __expf(lrelu02(as.x + ad.x + t0 * inv));
        o.y = __expf(lrelu02(as.y + ad.y + t1 * inv));
        o.z = __expf(lrelu02(as.z + ad.z + t2 * inv));
        o.w = __expf(lrelu02(as.w + ad.w + t3 * inv));
        *(float4*)(sp + n * 4) = o;
    }
}

// ======== shared edge-loop body: pure weighted gather (p precomputed) ========
__device__ __forceinline__ void acc8(float acc[8], float p, const uint4 g)
{
    acc[0] += p * bfl(g.x); acc[1] += p * bfh(g.x);
    acc[2] += p * bfl(g.y); acc[3] += p * bfh(g.y);
    acc[4] += p * bfl(g.z); acc[5] += p * bfh(g.z);
    acc[6] += p * bfl(g.w); acc[7] += p * bfh(g.w);
}

__device__ __forceinline__ void agg_loop(
    int beg, int end, int n, int head, int cbase,
    const int2* __restrict__ se, const float* __restrict__ p4,
    const float* __restrict__ sp, const ushort_t* __restrict__ hb,
    float acc[8], float& dh)
{
    // self-loop row: issue early so its latency hides under the edge loop
    const uint4 gs = *(const uint4*)(hb + (size_t)n * 512 + cbase);
    const float ps = sp[n * 4 + head];

    int j = beg;
    for (; j + 4 <= end; j += 4) {
        const int2 e0 = se[j],     e1 = se[j + 1];
        const int2 e2 = se[j + 2], e3 = se[j + 3];
        const float* pj = p4 + ((size_t)j * 4 + head);
        const float p0 = pj[0], p1 = pj[4], p2 = pj[8], p3 = pj[12];
        const uint4 g0 = *(const uint4*)(hb + (size_t)e0.x * 512 + cbase);
        const uint4 g1 = *(const uint4*)(hb + (size_t)e1.x * 512 + cbase);
        const uint4 g2 = *(const uint4*)(hb + (size_t)e2.x * 512 + cbase);
        const uint4 g3 = *(const uint4*)(hb + (size_t)e3.x * 512 + cbase);
        dh += (p0 + p1) + (p2 + p3);
        acc8(acc, p0, g0); acc8(acc, p1, g1);
        acc8(acc, p2, g2); acc8(acc, p3, g3);
    }
    for (; j + 2 <= end; j += 2) {
        const int2 e0 = se[j], e1 = se[j + 1];
        const float* pj = p4 + ((size_t)j * 4 + head);
        const float p0 = pj[0], p1 = pj[4];
        const uint4 g0 = *(const uint4*)(hb + (size_t)e0.x * 512 + cbase);
        const uint4 g1 = *(const uint4*)(hb + (size_t)e1.x * 512 + cbase);
        dh += p0 + p1;
        acc8(acc, p0, g0); acc8(acc, p1, g1);
    }
    if (j < end) {
        const int2 e0 = se[j];
        const float p0 = p4[(size_t)j * 4 + head];
        const uint4 g0 = *(const uint4*)(hb + (size_t)e0.x * 512 + cbase);
        dh += p0;
        acc8(acc, p0, g0);
    }
    // self-loop (fill_value='mean', p precomputed)
    dh += ps;
    acc8(acc, ps, gs);
}

// ===== L0 variant: bf16 A-layout out + FUSED next-layer a_s/a_d =====
__global__ __launch_bounds__(256) void node_agg_f_kernel(
    const int* __restrict__ ptr, const int2* __restrict__ se,
    const float* __restrict__ p4, const float* __restrict__ sp,
    const ushort_t* __restrict__ hb,
    const float* __restrict__ bias, ushort_t* __restrict__ oa,
    const float* __restrict__ wa_s2, const float* __restrict__ wa_d2,
    float* __restrict__ a_s2, float* __restrict__ a_d2)
{
    const int n = blockIdx.x * 4 + (threadIdx.x >> 6);
    const int lane = threadIdx.x & 63;
    if (n >= N_NODES) return;
    const int beg = ptr[n], end = ptr[n + 1];
    const int head = lane >> 4;
    const int cbase = lane * 8;

    float acc[8] = {};
    float dh = 0.f;
    agg_loop(beg, end, n, head, cbase, se, p4, sp, hb, acc, dh);

    const float ih = 0.25f / (dh + 1e-16f);
    float t[8];
    #pragma unroll
    for (int k = 0; k < 8; ++k) {
        t[k] = acc[k] * ih;
        t[k] += __shfl_xor(t[k], 16);
        t[k] += __shfl_xor(t[k], 32);
    }
    if (lane < 16) {
        const float4 b0 = *(const float4*)(bias + cbase);
        const float4 b1 = *(const float4*)(bias + cbase + 4);
        float o[8];
        o[0] = fmaxf(t[0] + b0.x, 0.f); o[1] = fmaxf(t[1] + b0.y, 0.f);
        o[2] = fmaxf(t[2] + b0.z, 0.f); o[3] = fmaxf(t[3] + b0.w, 0.f);
        o[4] = fmaxf(t[4] + b1.x, 0.f); o[5] = fmaxf(t[5] + b1.y, 0.f);
        o[6] = fmaxf(t[6] + b1.z, 0.f); o[7] = fmaxf(t[7] + b1.w, 0.f);
        unsigned int up[4];
        #pragma unroll
        for (int i = 0; i < 4; ++i)
            up[i] = (rnd16(o[2*i+1]) << 16) | rnd16(o[2*i]);
        *(uint4*)(oa + ((size_t)lane * MP + n) * 8) = make_uint4(up[0], up[1], up[2], up[3]);
        // fused next-layer a_s/a_d: per-head 128-dot over the output row
        float pss[4] = {0,0,0,0}, pdd[4] = {0,0,0,0};
        #pragma unroll
        for (int h = 0; h < NH; ++h) {
            const float* ws = wa_s2 + h * DIM + cbase;
            const float* wd = wa_d2 + h * DIM + cbase;
            #pragma unroll
            for (int i = 0; i < 8; ++i) {
                pss[h] += o[i] * ws[i];
                pdd[h] += o[i] * wd[i];
            }
        }
        #pragma unroll
        for (int m = 1; m < 16; m <<= 1) {
            #pragma unroll
            for (int h = 0; h < NH; ++h) {
                pss[h] += __shfl_xor(pss[h], m);
                pdd[h] += __shfl_xor(pdd[h], m);
            }
        }
        if (lane == 0) {
            float4 vs = {pss[0], pss[1], pss[2], pss[3]};
            float4 vd = {pdd[0], pdd[1], pdd[2], pdd[3]};
            *(float4*)(a_s2 + n * 4) = vs;
            *(float4*)(a_d2 + n * 4) = vd;
        }
    }
}

// ===== L1 variant: fp32 out only, no fusion =====
__global__ __launch_bounds__(256) void node_agg_s_kernel(
    const int* __restrict__ ptr, const int2* __restrict__ se,
    const float* __restrict__ p4, const float* __restrict__ sp,
    const ushort_t* __restrict__ hb,
    const float* __restrict__ bias, float* __restrict__ outf)
{
    const int n = blockIdx.x * 4 + (threadIdx.x >> 6);
    const int lane = threadIdx.x & 63;
    if (n >= N_NODES) return;
    const int beg = ptr[n], end = ptr[n + 1];
    const int head = lane >> 4;
    const int cbase = lane * 8;

    float acc[8] = {};
    float dh = 0.f;
    agg_loop(beg, end, n, head, cbase, se, p4, sp, hb, acc, dh);

    const float ih = 0.25f / (dh + 1e-16f);
    float t[8];
    #pragma unroll
    for (int k = 0; k < 8; ++k) {
        t[k] = acc[k] * ih;
        t[k] += __shfl_xor(t[k], 16);
        t[k] += __shfl_xor(t[k], 32);
    }
    if (lane < 16) {
        const float4 b0 = *(const float4*)(bias + cbase);
        const float4 b1 = *(const float4*)(bias + cbase + 4);
        float4 v0, v1;
        v0.x = fmaxf(t[0] + b0.x, 0.f); v0.y = fmaxf(t[1] + b0.y, 0.f);
        v0.z = fmaxf(t[2] + b0.z, 0.f); v0.w = fmaxf(t[3] + b0.w, 0.f);
        v1.x = fmaxf(t[4] + b1.x, 0.f); v1.y = fmaxf(t[5] + b1.y, 0.f);
        v1.z = fmaxf(t[6] + b1.z, 0.f); v1.w = fmaxf(t[7] + b1.w, 0.f);
        *(float4*)(outf + (size_t)n * DIM + cbase) = v0;
        *(float4*)(outf + (size_t)n * DIM + cbase + 4) = v1;
    }
}

extern "C" void kernel_launch(void* const* d_in, const int* in_sizes, int n_in,
                              void* d_out, int out_size, void* d_ws, size_t ws_size,
                              hipStream_t stream)
{
    const float* x       = (const float*)d_in[0];
    const int*   eidx    = (const int*)d_in[1];
    const int*   etype   = (const int*)d_in[2];
    const float* w1      = (const float*)d_in[3];
    const float* b1      = (const float*)d_in[4];
    const float* w2      = (const float*)d_in[5];
    const float* b2      = (const float*)d_in[6];
    const float* rel_emb = (const float*)d_in[7];
    const float* lin[2]  = {(const float*)d_in[8],  (const float*)d_in[14]};
    const float* line[2] = {(const float*)d_in[9],  (const float*)d_in[15]};
    const float* atts[2] = {(const float*)d_in[10], (const float*)d_in[16]};
    const float* attd[2] = {(const float*)d_in[11], (const float*)d_in[17]};
    const float* atte[2] = {(const float*)d_in[12], (const float*)d_in[18]};
    const float* bias[2] = {(const float*)d_in[13], (const float*)d_in[19]};
    const int* src = eidx;
    const int* dst = eidx + N_EDGES;

    // ---- workspace layout ----
    char* base = (char*)d_ws;
    size_t off = 0;
    auto alloc = [&](size_t bytes) -> void* {
        void* p = base + off;
        off = (off + bytes + 255) & ~(size_t)255;
        return p;
    };
    ushort_t* xh  = (ushort_t*)alloc((size_t)68 * MP * 8 * 2);  // hb overlays (dead after enc1)
    ushort_t* xl  = (ushort_t*)alloc((size_t)68 * MP * 8 * 2);
    ushort_t* h1h = (ushort_t*)alloc((size_t)32 * MP * 8 * 2);
    ushort_t* h1l = (ushort_t*)alloc((size_t)32 * MP * 8 * 2);
    ushort_t* x0a = (ushort_t*)alloc((size_t)16 * MP * 8 * 2);
    void* reg1    = alloc((size_t)16 * MP * 8 * 4);             // xbuf0 fp32 | x1a
    ushort_t* w1h = (ushort_t*)alloc(W1_T * 2);
    ushort_t* w1l = (ushort_t*)alloc(W1_T * 2);
    ushort_t* w2h = (ushort_t*)alloc(W2_T * 2);
    ushort_t* w2l = (ushort_t*)alloc(W2_T * 2);
    ushort_t* l0h = (ushort_t*)alloc(L_T * 2);
    ushort_t* l0l = (ushort_t*)alloc(L_T * 2);
    ushort_t* l1h = (ushort_t*)alloc(L_T * 2);
    ushort_t* l1l = (ushort_t*)alloc(L_T * 2);
    float* a_s0  = (float*)alloc(N_NODES * 4 * 4);
    float* a_d0  = (float*)alloc(N_NODES * 4 * 4);
    float* a_s1  = (float*)alloc(N_NODES * 4 * 4);
    float* a_d1  = (float*)alloc(N_NODES * 4 * 4);
    float* table = (float*)alloc(2 * 128 * 4);
    float* wa_s0 = (float*)alloc(512 * 4);
    float* wa_d0 = (float*)alloc(512 * 4);
    float* wa_s1 = (float*)alloc(512 * 4);
    float* wa_d1 = (float*)alloc(512 * 4);
    int*  cnt_i  = (int*)alloc(N_NODES * 4);
    int*  ptr    = (int*)alloc((N_NODES + 4) * 4);
    int*  ptrc   = (int*)alloc(N_NODES * 4);
    int2* se     = (int2*)alloc((size_t)N_EDGES * 8);
    int*  pose   = (int*)alloc((size_t)N_EDGES * 4);            // edge -> CSR pos
    float* p4    = (float*)alloc((size_t)N_EDGES * 4 * 4);      // per-edge p (layer-reused)
    float* sp    = (float*)alloc((size_t)N_NODES * 4 * 4);      // per-node self-loop p

    ushort_t* hb = xh;              // bf16 hfeat [MP][512], 20.5 MB (xh dead after enc1)
    float* xbuf0 = (float*)reg1;
    ushort_t* x1a = (ushort_t*)reg1;  // node_agg L0 bf16 A-layout out (xbuf0 dead after as_ad L0)

    const int mtiles = MP / 64;     // 313
    const int ep_grid = EP_EBLK + (N_NODES + 255) / 256;   // 1250 + 79

    // ---- input conversions (merged launches) ----
    conv_a_t_kernel<<<dim3(MP / 64, 9), 256, 0, stream>>>(x, xh, xl);
    conv_w_all_kernel<<<(W1_T + W2_T + 2 * L_T + 255) / 256, 256, 0, stream>>>(
        w1, w2, lin[0], lin[1], w1h, w1l, w2h, w2l, l0h, l0l, l1h, l1l);
    wa2_kernel<<<8, 256, 0, stream>>>(lin[0], lin[1], atts[0], attd[0], atts[1], attd[1],
                                      wa_s0, wa_d0, wa_s1, wa_d1);
    rel_table2_kernel<<<2, 128, 0, stream>>>(rel_emb, line[0], atte[0], line[1], atte[1], table);

    // ---- CSR build ----
    hipMemsetAsync(cnt_i, 0, N_NODES * sizeof(int), stream);
    hist_kernel<<<(N_EDGES + 255) / 256, 256, 0, stream>>>(dst, cnt_i);
    scan_kernel<<<1, 1024, 0, stream>>>(cnt_i, ptr, ptrc);
    scatter_kernel<<<(N_EDGES + 255) / 256, 256, 0, stream>>>(src, dst, etype, ptrc, se, pose);

    // ---- node encoder (3-term split) ----
    gemm_mfma_v2<<<dim3(HIDDEN / 128, mtiles), 256, 0, stream>>>(
        xh, xl, w1h, w1l, b1, N_NODES, 68, HIDDEN, 1, nullptr, h1h, h1l, nullptr, nullptr);
    gemm_mfma_v2<<<dim3(DIM / 128, mtiles), 256, 0, stream>>>(
        h1h, h1l, w2h, w2l, b2, N_NODES, 32, DIM, 0, xbuf0, nullptr, nullptr, nullptr, x0a);

    // ---- layer 0 (2-term: A quantized bf16) ----
    gemm_mfma_v2<<<dim3((NH * DIM) / 128, mtiles), 256, 0, stream>>>(
        x0a, nullptr, l0h, l0l, nullptr, N_NODES, 16, NH * DIM, 0, nullptr, nullptr, nullptr, hb, nullptr);
    as_ad_kernel<<<N_NODES, 256, 0, stream>>>(xbuf0, wa_s0, wa_d0, a_s0, a_d0);
    edge_self_p_kernel<<<ep_grid, 256, 0, stream>>>(
        src, dst, etype, pose, ptr, se, a_s0, a_d0, table, p4, sp);
    node_agg_f_kernel<<<(N_NODES + 3) / 4, 256, 0, stream>>>(
        ptr, se, p4, sp, hb, bias[0], x1a,
        wa_s1, wa_d1, a_s1, a_d1);

    // ---- layer 1 (2-term; a_s/a_d computed by node_agg L0) ----
    gemm_mfma_v2<<<dim3((NH * DIM) / 128, mtiles), 256, 0, stream>>>(
        x1a, nullptr, l1h, l1l, nullptr, N_NODES, 16, NH * DIM, 0, nullptr, nullptr, nullptr, hb, nullptr);
    edge_self_p_kernel<<<ep_grid, 256, 0, stream>>>(
        src, dst, etype, pose, ptr, se, a_s1, a_d1, table + 128, p4, sp);
    node_agg_s_kernel<<<(N_NODES + 3) / 4, 256, 0, stream>>>(
        ptr, se, p4, sp, hb, bias[1], (float*)d_out);
}

// Round 2
// 418.987 us; speedup vs baseline: 1.0413x; 1.0413x over previous
//
#include <hip/hip_runtime.h>
#include <math.h>

#define N_NODES 20000
#define MP      20032          // M padded to 64
#define N_EDGES 320000
#define F_IN    518
#define HIDDEN  256
#define DIM     128
#define NH      4

typedef __attribute__((ext_vector_type(8))) short bf16x8;
typedef __attribute__((ext_vector_type(4))) float f32x4;
typedef unsigned short ushort_t;

__device__ __forceinline__ float lrelu02(float x) { return x > 0.f ? x : 0.2f * x; }

__device__ __forceinline__ void gl_lds16(const void* g, void* l) {
    __builtin_amdgcn_global_load_lds(
        (const __attribute__((address_space(1))) unsigned int*)g,
        (__attribute__((address_space(3))) unsigned int*)l, 16, 0, 0);
}

__device__ __forceinline__ unsigned int hi16(float v) { return __float_as_uint(v) >> 16; }
__device__ __forceinline__ unsigned int lo16(float v) {
    unsigned int h = __float_as_uint(v) & 0xFFFF0000u;
    return __float_as_uint(v - __uint_as_float(h)) >> 16;
}
// round-to-nearest-even bf16
__device__ __forceinline__ unsigned int rnd16(float v) {
    unsigned int u = __float_as_uint(v);
    return (u + 0x7FFFu + ((u >> 16) & 1u)) >> 16;
}
__device__ __forceinline__ float bfl(unsigned int u) { return __uint_as_float(u << 16); }
__device__ __forceinline__ float bfh(unsigned int u) { return __uint_as_float(u & 0xFFFF0000u); }

// ====== split-bf16 MFMA GEMM, operands pre-split, k-chunk-major ======
__global__ __launch_bounds__(256, 4) void gemm_mfma_v2(
    const ushort_t* __restrict__ Ah, const ushort_t* __restrict__ Al,
    const ushort_t* __restrict__ Bh, const ushort_t* __restrict__ Bl,
    const float* __restrict__ bias,
    int M, int K8, int N, int act,
    float* __restrict__ Cf,                                      // fp32 [M][N]
    ushort_t* __restrict__ Ch, ushort_t* __restrict__ Cl,        // split A-layout
    ushort_t* __restrict__ Cb,                                   // plain bf16 [M][N]
    ushort_t* __restrict__ Ca)                                   // plain bf16 A-layout
{
    __shared__ __align__(16) ushort_t lds[12288];
    const int tid = threadIdx.x;
    const int w = tid >> 6, lane = tid & 63;
    const int row0 = blockIdx.y * 64, col0 = blockIdx.x * 128;
    const int nkb = K8 >> 2;
    const int m16 = lane & 15, q = lane >> 4;
    const bool use_al = (Al != nullptr);

    f32x4 acc[4][2] = {};

    for (int kb = 0; kb < nkb; ++kb) {
        const size_t kc = (size_t)(kb * 4 + w);
        const size_t aoff = (kc * MP + row0) * 8 + lane * 8;
        const size_t boff = (kc * N + col0) * 8 + lane * 8;
        gl_lds16(Ah + aoff, &lds[w * 512]);
        if (use_al) gl_lds16(Al + aoff, &lds[2048 + w * 512]);
        gl_lds16(Bh + boff,       &lds[4096 + w * 1024]);
        gl_lds16(Bh + boff + 512, &lds[4096 + w * 1024 + 512]);
        gl_lds16(Bl + boff,       &lds[8192 + w * 1024]);
        gl_lds16(Bl + boff + 512, &lds[8192 + w * 1024 + 512]);
        __syncthreads();

        bf16x8 fah[4], fal[4], fbh[2], fbl[2];
        const int fa = q * 512 + m16 * 8;
        #pragma unroll
        for (int mi = 0; mi < 4; ++mi) {
            fah[mi] = *(const bf16x8*)&lds[fa + mi * 128];
            if (use_al) fal[mi] = *(const bf16x8*)&lds[2048 + fa + mi * 128];
        }
        const int fb = q * 1024 + (w * 32 + m16) * 8;
        #pragma unroll
        for (int ni = 0; ni < 2; ++ni) {
            fbh[ni] = *(const bf16x8*)&lds[4096 + fb + ni * 128];
            fbl[ni] = *(const bf16x8*)&lds[8192 + fb + ni * 128];
        }
        #pragma unroll
        for (int mi = 0; mi < 4; ++mi)
            #pragma unroll
            for (int ni = 0; ni < 2; ++ni) {
                acc[mi][ni] = __builtin_amdgcn_mfma_f32_16x16x32_bf16(fah[mi], fbh[ni], acc[mi][ni], 0, 0, 0);
                acc[mi][ni] = __builtin_amdgcn_mfma_f32_16x16x32_bf16(fah[mi], fbl[ni], acc[mi][ni], 0, 0, 0);
            }
        if (use_al) {
            #pragma unroll
            for (int mi = 0; mi < 4; ++mi)
                #pragma unroll
                for (int ni = 0; ni < 2; ++ni)
                    acc[mi][ni] = __builtin_amdgcn_mfma_f32_16x16x32_bf16(fal[mi], fbh[ni], acc[mi][ni], 0, 0, 0);
        }
        __syncthreads();
    }

    // epilogue: C/D row=(lane>>4)*4+reg, col=lane&15
    #pragma unroll
    for (int ni = 0; ni < 2; ++ni) {
        const int col = col0 + w * 32 + ni * 16 + m16;
        const float bb = bias ? bias[col] : 0.f;
        #pragma unroll
        for (int mi = 0; mi < 4; ++mi) {
            #pragma unroll
            for (int r = 0; r < 4; ++r) {
                const int row = row0 + mi * 16 + q * 4 + r;
                if (row < M) {
                    float v = acc[mi][ni][r] + bb;
                    if (act) v = fmaxf(v, 0.f);
                    if (Cf) Cf[(size_t)row * N + col] = v;
                    if (Cb) Cb[(size_t)row * N + col] = (ushort_t)rnd16(v);
                    const size_t p = (((size_t)(col >> 3)) * MP + row) * 8 + (col & 7);
                    if (Ch) { Ch[p] = (ushort_t)hi16(v); Cl[p] = (ushort_t)lo16(v); }
                    if (Ca) Ca[p] = (ushort_t)rnd16(v);
                }
            }
        }
    }
}

// ---- x fp32 [N_NODES][F_IN] -> xh/xl bf16 [K8][MP][8], coalesced via LDS tile ----
__global__ __launch_bounds__(256) void conv_a_t_kernel(
    const float* __restrict__ x, ushort_t* __restrict__ xh, ushort_t* __restrict__ xl)
{
    __shared__ float tile[64][68];
    const int tid = threadIdx.x;
    const int r0 = blockIdx.x * 64;
    const int c0 = blockIdx.y * 64;

    #pragma unroll
    for (int it = 0; it < 4; ++it) {
        const int r = (tid >> 4) + it * 16;
        const int c = (tid & 15) * 4;
        const int gr = r0 + r, gc = c0 + c;
        float4 v = {0.f, 0.f, 0.f, 0.f};
        if (gr < N_NODES) {
            if (gc + 3 < F_IN) {
                v = *(const float4*)(x + (size_t)gr * F_IN + gc);
            } else {
                float tmp[4] = {0.f, 0.f, 0.f, 0.f};
                #pragma unroll
                for (int u = 0; u < 4; ++u)
                    if (gc + u < F_IN) tmp[u] = x[(size_t)gr * F_IN + gc + u];
                v.x = tmp[0]; v.y = tmp[1]; v.z = tmp[2]; v.w = tmp[3];
            }
        }
        tile[r][c] = v.x; tile[r][c+1] = v.y; tile[r][c+2] = v.z; tile[r][c+3] = v.w;
    }
    __syncthreads();

    const int k8l = tid >> 5;
    const int k8 = (c0 >> 3) + k8l;
    if (k8 >= 68) return;
    const int rr = (tid & 31) * 2;
    #pragma unroll
    for (int u = 0; u < 2; ++u) {
        const int r = rr + u;
        unsigned int hp[4], lp[4];
        #pragma unroll
        for (int i = 0; i < 4; ++i) {
            const float v0 = tile[r][k8l * 8 + 2 * i];
            const float v1 = tile[r][k8l * 8 + 2 * i + 1];
            hp[i] = (hi16(v1) << 16) | hi16(v0);
            lp[i] = (lo16(v1) << 16) | lo16(v0);
        }
        const size_t p = ((size_t)k8 * MP + r0 + r) * 8;
        *(uint4*)(xh + p) = make_uint4(hp[0], hp[1], hp[2], hp[3]);
        *(uint4*)(xl + p) = make_uint4(lp[0], lp[1], lp[2], lp[3]);
    }
}

// ---- all 4 weights fp32 -> bf16 hi/lo [K8][N][8] in ONE launch ----
#define W1_T (68 * 256 * 8)
#define W2_T (32 * 128 * 8)
#define L_T  (16 * 512 * 8)
__global__ __launch_bounds__(256) void conv_w_all_kernel(
    const float* __restrict__ w1, const float* __restrict__ w2,
    const float* __restrict__ l0, const float* __restrict__ l1,
    ushort_t* __restrict__ w1h, ushort_t* __restrict__ w1l,
    ushort_t* __restrict__ w2h, ushort_t* __restrict__ w2l,
    ushort_t* __restrict__ l0h, ushort_t* __restrict__ l0l,
    ushort_t* __restrict__ l1h, ushort_t* __restrict__ l1l)
{
    int idx = blockIdx.x * 256 + threadIdx.x;
    const float* w; ushort_t *bh, *bl; int K, N, local;
    if (idx < W1_T) { w = w1; bh = w1h; bl = w1l; K = F_IN; N = HIDDEN; local = idx; }
    else if (idx < W1_T + W2_T) { w = w2; bh = w2h; bl = w2l; K = HIDDEN; N = DIM; local = idx - W1_T; }
    else if (idx < W1_T + W2_T + L_T) { w = l0; bh = l0h; bl = l0l; K = DIM; N = 512; local = idx - W1_T - W2_T; }
    else if (idx < W1_T + W2_T + 2 * L_T) { w = l1; bh = l1h; bl = l1l; K = DIM; N = 512; local = idx - W1_T - W2_T - L_T; }
    else return;
    const int j = local & 7;
    const int rem = local >> 3;
    const int n = rem % N;
    const int k = (rem / N) * 8 + j;
    const float v = (k < K) ? w[(size_t)k * N + n] : 0.f;
    bh[local] = (ushort_t)hi16(v);
    bl[local] = (ushort_t)lo16(v);
}

// ---- wa for BOTH layers in one launch ----
__global__ __launch_bounds__(256) void wa2_kernel(
    const float* __restrict__ lin0, const float* __restrict__ lin1,
    const float* __restrict__ atts0, const float* __restrict__ attd0,
    const float* __restrict__ atts1, const float* __restrict__ attd1,
    float* __restrict__ wa_s0, float* __restrict__ wa_d0,
    float* __restrict__ wa_s1, float* __restrict__ wa_d1)
{
    const int wrk = blockIdx.x * 256 + threadIdx.x;
    if (wrk >= 2048) return;
    const int L = wrk >> 10;
    const int sd = (wrk >> 9) & 1;
    const int p = wrk & 511;
    const int h = p >> 7, d = p & 127;
    const float* lin = L ? lin1 : lin0;
    const float* av = L ? (sd ? attd1 : atts1) : (sd ? attd0 : atts0);
    float* out = L ? (sd ? wa_d1 : wa_s1) : (sd ? wa_d0 : wa_s0);
    const float* lp = lin + (size_t)d * (NH * DIM) + h * DIM;
    const float* ap = av + h * DIM;
    float acc = 0.f;
    #pragma unroll 8
    for (int i = 0; i < DIM; ++i) acc += lp[i] * ap[i];
    out[h * DIM + d] = acc;
}

// ---- a_s[n,h], a_d[n,h] from xbuf (fp32 [N][128]) ----
__global__ __launch_bounds__(256) void as_ad_kernel(
    const float* __restrict__ xb, const float* __restrict__ wa_s,
    const float* __restrict__ wa_d, float* __restrict__ a_s, float* __restrict__ a_d)
{
    const int gw = blockIdx.x * 4 + (threadIdx.x >> 6);
    const int lane = threadIdx.x & 63;
    if (gw >= N_NODES * NH) return;
    const int n = gw >> 2, h = gw & 3;
    const float* hp = xb + (size_t)n * DIM;
    float2 hv = *(const float2*)(hp + lane * 2);
    float2 sv = *(const float2*)(wa_s + h * DIM + lane * 2);
    float2 dv = *(const float2*)(wa_d + h * DIM + lane * 2);
    float s = hv.x * sv.x + hv.y * sv.y;
    float d = hv.x * dv.x + hv.y * dv.y;
    #pragma unroll
    for (int off = 32; off > 0; off >>= 1) {
        s += __shfl_down(s, off);
        d += __shfl_down(d, off);
    }
    if (lane == 0) { a_s[n * 4 + h] = s; a_d[n * 4 + h] = d; }
}

// ---- rel attention tables for BOTH layers: blockIdx.x = layer ----
__global__ __launch_bounds__(128) void rel_table2_kernel(
    const float* __restrict__ rel_emb,
    const float* __restrict__ line0, const float* __restrict__ atte0,
    const float* __restrict__ line1, const float* __restrict__ atte1,
    float* __restrict__ table)          // [2][128]
{
    __shared__ float we[32][NH];
    const int L = blockIdx.x;
    const float* line = L ? line1 : line0;
    const float* atte = L ? atte1 : atte0;
    float* tab = table + L * 128;
    const int tid = threadIdx.x;
    const int k = tid >> 2, h = tid & 3;
    float acc = 0.f;
    for (int d = 0; d < DIM; ++d)
        acc += line[(size_t)k * (NH * DIM) + h * DIM + d] * atte[h * DIM + d];
    we[k][h] = acc;
    __syncthreads();
    if (tid < 26 * NH) {
        int r = tid >> 2, hh = tid & 3;
        float t = 0.f;
        for (int kk = 0; kk < 32; ++kk) t += rel_emb[r * 32 + kk] * we[kk][hh];
        tab[r * 4 + hh] = t;
    }
}

// ================= CSR build =================
__global__ __launch_bounds__(256) void hist_kernel(
    const int* __restrict__ dst, int* __restrict__ cnt)
{
    const int e = blockIdx.x * blockDim.x + threadIdx.x;
    if (e >= N_EDGES) return;
    atomicAdd(&cnt[dst[e]], 1);
}

__global__ __launch_bounds__(1024) void scan_kernel(
    const int* __restrict__ cnt, int* __restrict__ ptr, int* __restrict__ ptr_copy)
{
    __shared__ int tsum[1024];
    const int tid = threadIdx.x;
    const int CH = 20;
    const int base = tid * CH;
    int s = 0;
    #pragma unroll
    for (int i = 0; i < CH; ++i) {
        int idx = base + i;
        if (idx < N_NODES) s += cnt[idx];
    }
    tsum[tid] = s;
    __syncthreads();
    for (int off = 1; off < 1024; off <<= 1) {
        int v = (tid >= off) ? tsum[tid - off] : 0;
        __syncthreads();
        tsum[tid] += v;
        __syncthreads();
    }
    int run = (tid == 0) ? 0 : tsum[tid - 1];
    #pragma unroll
    for (int i = 0; i < CH; ++i) {
        int idx = base + i;
        if (idx < N_NODES) {
            ptr[idx] = run;
            ptr_copy[idx] = run;
            run += cnt[idx];
        }
    }
    if (tid == 0) ptr[N_NODES] = N_EDGES;
}

__global__ __launch_bounds__(256) void scatter_kernel(
    const int* __restrict__ src, const int* __restrict__ dst, const int* __restrict__ etype,
    int* __restrict__ ptr_copy, int2* __restrict__ se, int* __restrict__ dcsr)
{
    const int e = blockIdx.x * blockDim.x + threadIdx.x;
    if (e >= N_EDGES) return;
    const int d = dst[e];
    const int pos = atomicAdd(&ptr_copy[d], 1);
    se[pos] = make_int2(src[e], etype[e]);
    dcsr[pos] = d;
}

// ======== per-edge softmax numerator p[j][h], CSR-ordered, fully coalesced ========
// 2 edges per thread: se/dcsr reads and p4 writes are 16B/lane contiguous;
// a_d[d] is CSR-sorted (L1 broadcast); only a_s[src] is a true gather.
__global__ __launch_bounds__(256) void edge_p_kernel(
    const int2* __restrict__ se, const int* __restrict__ dcsr,
    const float* __restrict__ a_s, const float* __restrict__ a_d,
    const float* __restrict__ table, float* __restrict__ p4)
{
    const int j0 = (blockIdx.x * 256 + threadIdx.x) * 2;
    const int2 eA = se[j0], eB = se[j0 + 1];
    const int dA = dcsr[j0], dB = dcsr[j0 + 1];
    const float4 asA = *(const float4*)(a_s + eA.x * 4);
    const float4 asB = *(const float4*)(a_s + eB.x * 4);
    const float4 adA = *(const float4*)(a_d + dA * 4);
    const float4 adB = *(const float4*)(a_d + dB * 4);
    const float4 tA  = *(const float4*)(table + eA.y * 4);
    const float4 tB  = *(const float4*)(table + eB.y * 4);
    float4 oA, oB;
    oA.x = __expf(lrelu02(asA.x + adA.x + tA.x));
    oA.y = __expf(lrelu02(asA.y + adA.y + tA.y));
    oA.z = __expf(lrelu02(asA.z + adA.z + tA.z));
    oA.w = __expf(lrelu02(asA.w + adA.w + tA.w));
    oB.x = __expf(lrelu02(asB.x + adB.x + tB.x));
    oB.y = __expf(lrelu02(asB.y + adB.y + tB.y));
    oB.z = __expf(lrelu02(asB.z + adB.z + tB.z));
    oB.w = __expf(lrelu02(asB.w + adB.w + tB.w));
    *(float4*)(p4 + (size_t)j0 * 4)     = oA;
    *(float4*)(p4 + (size_t)j0 * 4 + 4) = oB;
}

// ======== shared edge-loop body: weighted gather + eh table-sum ========
__device__ __forceinline__ void acc8(float acc[8], float p, const uint4 g)
{
    acc[0] += p * bfl(g.x); acc[1] += p * bfh(g.x);
    acc[2] += p * bfl(g.y); acc[3] += p * bfh(g.y);
    acc[4] += p * bfl(g.z); acc[5] += p * bfh(g.z);
    acc[6] += p * bfl(g.w); acc[7] += p * bfh(g.w);
}

__device__ __forceinline__ void agg_loop(
    int beg, int end, int n, int head, int cbase,
    const int2* __restrict__ se, const float* __restrict__ p4,
    const float* __restrict__ table, const float* __restrict__ a_s, float adh,
    const ushort_t* __restrict__ hb, float acc[8], float& dh)
{
    // self-loop row: issue early so its latency hides under the edge loop
    const uint4 gs = *(const uint4*)(hb + (size_t)n * 512 + cbase);

    float eh = 0.f;
    int j = beg;
    for (; j + 4 <= end; j += 4) {
        const int2 e0 = se[j],     e1 = se[j + 1];
        const int2 e2 = se[j + 2], e3 = se[j + 3];
        const float* pj = p4 + ((size_t)j * 4 + head);
        const float p0 = pj[0], p1 = pj[4], p2 = pj[8], p3 = pj[12];
        const uint4 g0 = *(const uint4*)(hb + (size_t)e0.x * 512 + cbase);
        const uint4 g1 = *(const uint4*)(hb + (size_t)e1.x * 512 + cbase);
        const uint4 g2 = *(const uint4*)(hb + (size_t)e2.x * 512 + cbase);
        const uint4 g3 = *(const uint4*)(hb + (size_t)e3.x * 512 + cbase);
        eh += (table[e0.y * 4 + head] + table[e1.y * 4 + head])
            + (table[e2.y * 4 + head] + table[e3.y * 4 + head]);
        dh += (p0 + p1) + (p2 + p3);
        acc8(acc, p0, g0); acc8(acc, p1, g1);
        acc8(acc, p2, g2); acc8(acc, p3, g3);
    }
    for (; j + 2 <= end; j += 2) {
        const int2 e0 = se[j], e1 = se[j + 1];
        const float* pj = p4 + ((size_t)j * 4 + head);
        const float p0 = pj[0], p1 = pj[4];
        const uint4 g0 = *(const uint4*)(hb + (size_t)e0.x * 512 + cbase);
        const uint4 g1 = *(const uint4*)(hb + (size_t)e1.x * 512 + cbase);
        eh += table[e0.y * 4 + head] + table[e1.y * 4 + head];
        dh += p0 + p1;
        acc8(acc, p0, g0); acc8(acc, p1, g1);
    }
    if (j < end) {
        const int2 e0 = se[j];
        const float p0 = p4[(size_t)j * 4 + head];
        const uint4 g0 = *(const uint4*)(hb + (size_t)e0.x * 512 + cbase);
        eh += table[e0.y * 4 + head];
        dh += p0;
        acc8(acc, p0, g0);
    }
    // self-loop (fill_value='mean')
    const float inv = 1.0f / fmaxf((float)(end - beg), 1.0f);
    const float ps = __expf(lrelu02(a_s[n * 4 + head] + adh + eh * inv));
    dh += ps;
    acc8(acc, ps, gs);
}

// ===== L0 variant: bf16 A-layout out + FUSED next-layer a_s/a_d =====
__global__ __launch_bounds__(256) void node_agg_f_kernel(
    const int* __restrict__ ptr, const int2* __restrict__ se,
    const float* __restrict__ p4, const float* __restrict__ table,
    const float* __restrict__ a_s, const float* __restrict__ a_d,
    const ushort_t* __restrict__ hb,
    const float* __restrict__ bias, ushort_t* __restrict__ oa,
    const float* __restrict__ wa_s2, const float* __restrict__ wa_d2,
    float* __restrict__ a_s2, float* __restrict__ a_d2)
{
    const int n = blockIdx.x * 4 + (threadIdx.x >> 6);
    const int lane = threadIdx.x & 63;
    if (n >= N_NODES) return;
    const int beg = ptr[n], end = ptr[n + 1];
    const int head = lane >> 4;
    const int cbase = lane * 8;
    const float adh = a_d[n * 4 + head];

    float acc[8] = {};
    float dh = 0.f;
    agg_loop(beg, end, n, head, cbase, se, p4, table, a_s, adh, hb, acc, dh);

    const float ih = 0.25f / (dh + 1e-16f);
    float t[8];
    #pragma unroll
    for (int k = 0; k < 8; ++k) {
        t[k] = acc[k] * ih;
        t[k] += __shfl_xor(t[k], 16);
        t[k] += __shfl_xor(t[k], 32);
    }
    if (lane < 16) {
        const float4 b0 = *(const float4*)(bias + cbase);
        const float4 b1 = *(const float4*)(bias + cbase + 4);
        float o[8];
        o[0] = fmaxf(t[0] + b0.x, 0.f); o[1] = fmaxf(t[1] + b0.y, 0.f);
        o[2] = fmaxf(t[2] + b0.z, 0.f); o[3] = fmaxf(t[3] + b0.w, 0.f);
        o[4] = fmaxf(t[4] + b1.x, 0.f); o[5] = fmaxf(t[5] + b1.y, 0.f);
        o[6] = fmaxf(t[6] + b1.z, 0.f); o[7] = fmaxf(t[7] + b1.w, 0.f);
        unsigned int up[4];
        #pragma unroll
        for (int i = 0; i < 4; ++i)
            up[i] = (rnd16(o[2*i+1]) << 16) | rnd16(o[2*i]);
        *(uint4*)(oa + ((size_t)lane * MP + n) * 8) = make_uint4(up[0], up[1], up[2], up[3]);
        // fused next-layer a_s/a_d: per-head 128-dot over the output row
        float pss[4] = {0,0,0,0}, pdd[4] = {0,0,0,0};
        #pragma unroll
        for (int h = 0; h < NH; ++h) {
            const float* ws = wa_s2 + h * DIM + cbase;
            const float* wd = wa_d2 + h * DIM + cbase;
            #pragma unroll
            for (int i = 0; i < 8; ++i) {
                pss[h] += o[i] * ws[i];
                pdd[h] += o[i] * wd[i];
            }
        }
        #pragma unroll
        for (int m = 1; m < 16; m <<= 1) {
            #pragma unroll
            for (int h = 0; h < NH; ++h) {
                pss[h] += __shfl_xor(pss[h], m);
                pdd[h] += __shfl_xor(pdd[h], m);
            }
        }
        if (lane == 0) {
            float4 vs = {pss[0], pss[1], pss[2], pss[3]};
            float4 vd = {pdd[0], pdd[1], pdd[2], pdd[3]};
            *(float4*)(a_s2 + n * 4) = vs;
            *(float4*)(a_d2 + n * 4) = vd;
        }
    }
}

// ===== L1 variant: fp32 out only, no fusion =====
__global__ __launch_bounds__(256) void node_agg_s_kernel(
    const int* __restrict__ ptr, const int2* __restrict__ se,
    const float* __restrict__ p4, const float* __restrict__ table,
    const float* __restrict__ a_s, const float* __restrict__ a_d,
    const ushort_t* __restrict__ hb,
    const float* __restrict__ bias, float* __restrict__ outf)
{
    const int n = blockIdx.x * 4 + (threadIdx.x >> 6);
    const int lane = threadIdx.x & 63;
    if (n >= N_NODES) return;
    const int beg = ptr[n], end = ptr[n + 1];
    const int head = lane >> 4;
    const int cbase = lane * 8;
    const float adh = a_d[n * 4 + head];

    float acc[8] = {};
    float dh = 0.f;
    agg_loop(beg, end, n, head, cbase, se, p4, table, a_s, adh, hb, acc, dh);

    const float ih = 0.25f / (dh + 1e-16f);
    float t[8];
    #pragma unroll
    for (int k = 0; k < 8; ++k) {
        t[k] = acc[k] * ih;
        t[k] += __shfl_xor(t[k], 16);
        t[k] += __shfl_xor(t[k], 32);
    }
    if (lane < 16) {
        const float4 b0 = *(const float4*)(bias + cbase);
        const float4 b1 = *(const float4*)(bias + cbase + 4);
        float4 v0, v1;
        v0.x = fmaxf(t[0] + b0.x, 0.f); v0.y = fmaxf(t[1] + b0.y, 0.f);
        v0.z = fmaxf(t[2] + b0.z, 0.f); v0.w = fmaxf(t[3] + b0.w, 0.f);
        v1.x = fmaxf(t[4] + b1.x, 0.f); v1.y = fmaxf(t[5] + b1.y, 0.f);
        v1.z = fmaxf(t[6] + b1.z, 0.f); v1.w = fmaxf(t[7] + b1.w, 0.f);
        *(float4*)(outf + (size_t)n * DIM + cbase) = v0;
        *(float4*)(outf + (size_t)n * DIM + cbase + 4) = v1;
    }
}

extern "C" void kernel_launch(void* const* d_in, const int* in_sizes, int n_in,
                              void* d_out, int out_size, void* d_ws, size_t ws_size,
                              hipStream_t stream)
{
    const float* x       = (const float*)d_in[0];
    const int*   eidx    = (const int*)d_in[1];
    const int*   etype   = (const int*)d_in[2];
    const float* w1      = (const float*)d_in[3];
    const float* b1      = (const float*)d_in[4];
    const float* w2      = (const float*)d_in[5];
    const float* b2      = (const float*)d_in[6];
    const float* rel_emb = (const float*)d_in[7];
    const float* lin[2]  = {(const float*)d_in[8],  (const float*)d_in[14]};
    const float* line[2] = {(const float*)d_in[9],  (const float*)d_in[15]};
    const float* atts[2] = {(const float*)d_in[10], (const float*)d_in[16]};
    const float* attd[2] = {(const float*)d_in[11], (const float*)d_in[17]};
    const float* atte[2] = {(const float*)d_in[12], (const float*)d_in[18]};
    const float* bias[2] = {(const float*)d_in[13], (const float*)d_in[19]};
    const int* src = eidx;
    const int* dst = eidx + N_EDGES;

    // ---- workspace layout ----
    char* base = (char*)d_ws;
    size_t off = 0;
    auto alloc = [&](size_t bytes) -> void* {
        void* p = base + off;
        off = (off + bytes + 255) & ~(size_t)255;
        return p;
    };
    ushort_t* xh  = (ushort_t*)alloc((size_t)68 * MP * 8 * 2);  // hb overlays (dead after enc1)
    ushort_t* xl  = (ushort_t*)alloc((size_t)68 * MP * 8 * 2);
    ushort_t* h1h = (ushort_t*)alloc((size_t)32 * MP * 8 * 2);
    ushort_t* h1l = (ushort_t*)alloc((size_t)32 * MP * 8 * 2);
    ushort_t* x0a = (ushort_t*)alloc((size_t)16 * MP * 8 * 2);
    void* reg1    = alloc((size_t)16 * MP * 8 * 4);             // xbuf0 fp32 | x1a
    ushort_t* w1h = (ushort_t*)alloc(W1_T * 2);
    ushort_t* w1l = (ushort_t*)alloc(W1_T * 2);
    ushort_t* w2h = (ushort_t*)alloc(W2_T * 2);
    ushort_t* w2l = (ushort_t*)alloc(W2_T * 2);
    ushort_t* l0h = (ushort_t*)alloc(L_T * 2);
    ushort_t* l0l = (ushort_t*)alloc(L_T * 2);
    ushort_t* l1h = (ushort_t*)alloc(L_T * 2);
    ushort_t* l1l = (ushort_t*)alloc(L_T * 2);
    float* a_s0  = (float*)alloc(N_NODES * 4 * 4);
    float* a_d0  = (float*)alloc(N_NODES * 4 * 4);
    float* a_s1  = (float*)alloc(N_NODES * 4 * 4);
    float* a_d1  = (float*)alloc(N_NODES * 4 * 4);
    float* table = (float*)alloc(2 * 128 * 4);
    float* wa_s0 = (float*)alloc(512 * 4);
    float* wa_d0 = (float*)alloc(512 * 4);
    float* wa_s1 = (float*)alloc(512 * 4);
    float* wa_d1 = (float*)alloc(512 * 4);
    int*  cnt_i  = (int*)alloc(N_NODES * 4);
    int*  ptr    = (int*)alloc((N_NODES + 4) * 4);
    int*  ptrc   = (int*)alloc(N_NODES * 4);
    int2* se     = (int2*)alloc((size_t)N_EDGES * 8);
    int*  dcsr   = (int*)alloc((size_t)N_EDGES * 4);            // CSR pos -> dst node
    float* p4    = (float*)alloc((size_t)N_EDGES * 4 * 4);      // per-edge p (layer-reused)

    ushort_t* hb = xh;              // bf16 hfeat [MP][512], 20.5 MB (xh dead after enc1)
    float* xbuf0 = (float*)reg1;
    ushort_t* x1a = (ushort_t*)reg1;  // node_agg L0 bf16 A-layout out (xbuf0 dead after as_ad L0)

    const int mtiles = MP / 64;     // 313
    const int ep_grid = N_EDGES / 512;   // 625, exact

    // ---- input conversions (merged launches) ----
    conv_a_t_kernel<<<dim3(MP / 64, 9), 256, 0, stream>>>(x, xh, xl);
    conv_w_all_kernel<<<(W1_T + W2_T + 2 * L_T + 255) / 256, 256, 0, stream>>>(
        w1, w2, lin[0], lin[1], w1h, w1l, w2h, w2l, l0h, l0l, l1h, l1l);
    wa2_kernel<<<8, 256, 0, stream>>>(lin[0], lin[1], atts[0], attd[0], atts[1], attd[1],
                                      wa_s0, wa_d0, wa_s1, wa_d1);
    rel_table2_kernel<<<2, 128, 0, stream>>>(rel_emb, line[0], atte[0], line[1], atte[1], table);

    // ---- CSR build ----
    hipMemsetAsync(cnt_i, 0, N_NODES * sizeof(int), stream);
    hist_kernel<<<(N_EDGES + 255) / 256, 256, 0, stream>>>(dst, cnt_i);
    scan_kernel<<<1, 1024, 0, stream>>>(cnt_i, ptr, ptrc);
    scatter_kernel<<<(N_EDGES + 255) / 256, 256, 0, stream>>>(src, dst, etype, ptrc, se, dcsr);

    // ---- node encoder (3-term split) ----
    gemm_mfma_v2<<<dim3(HIDDEN / 128, mtiles), 256, 0, stream>>>(
        xh, xl, w1h, w1l, b1, N_NODES, 68, HIDDEN, 1, nullptr, h1h, h1l, nullptr, nullptr);
    gemm_mfma_v2<<<dim3(DIM / 128, mtiles), 256, 0, stream>>>(
        h1h, h1l, w2h, w2l, b2, N_NODES, 32, DIM, 0, xbuf0, nullptr, nullptr, nullptr, x0a);

    // ---- layer 0 (2-term: A quantized bf16) ----
    gemm_mfma_v2<<<dim3((NH * DIM) / 128, mtiles), 256, 0, stream>>>(
        x0a, nullptr, l0h, l0l, nullptr, N_NODES, 16, NH * DIM, 0, nullptr, nullptr, nullptr, hb, nullptr);
    as_ad_kernel<<<N_NODES, 256, 0, stream>>>(xbuf0, wa_s0, wa_d0, a_s0, a_d0);
    edge_p_kernel<<<ep_grid, 256, 0, stream>>>(se, dcsr, a_s0, a_d0, table, p4);
    node_agg_f_kernel<<<(N_NODES + 3) / 4, 256, 0, stream>>>(
        ptr, se, p4, table, a_s0, a_d0, hb, bias[0], x1a,
        wa_s1, wa_d1, a_s1, a_d1);

    // ---- layer 1 (2-term; a_s/a_d computed by node_agg L0) ----
    gemm_mfma_v2<<<dim3((NH * DIM) / 128, mtiles), 256, 0, stream>>>(
        x1a, nullptr, l1h, l1l, nullptr, N_NODES, 16, NH * DIM, 0, nullptr, nullptr, nullptr, hb, nullptr);
    edge_p_kernel<<<ep_grid, 256, 0, stream>>>(se, dcsr, a_s1, a_d1, table + 128, p4);
    node_agg_s_kernel<<<(N_NODES + 3) / 4, 256, 0, stream>>>(
        ptr, se, p4, table + 128, a_s1, a_d1, hb, bias[1], (float*)d_out);
}

// Round 4
// 412.923 us; speedup vs baseline: 1.0566x; 1.0147x over previous
//
#include <hip/hip_runtime.h>
#include <math.h>

#define N_NODES 20000
#define MP      20032          // M padded to 64
#define N_EDGES 320000
#define F_IN    518
#define HIDDEN  256
#define DIM     128
#define NH      4

typedef __attribute__((ext_vector_type(8))) short bf16x8;
typedef __attribute__((ext_vector_type(4))) float f32x4;
typedef unsigned short ushort_t;

__device__ __forceinline__ float lrelu02(float x) { return x > 0.f ? x : 0.2f * x; }

__device__ __forceinline__ void gl_lds16(const void* g, void* l) {
    __builtin_amdgcn_global_load_lds(
        (const __attribute__((address_space(1))) unsigned int*)g,
        (__attribute__((address_space(3))) unsigned int*)l, 16, 0, 0);
}

__device__ __forceinline__ unsigned int hi16(float v) { return __float_as_uint(v) >> 16; }
__device__ __forceinline__ unsigned int lo16(float v) {
    unsigned int h = __float_as_uint(v) & 0xFFFF0000u;
    return __float_as_uint(v - __uint_as_float(h)) >> 16;
}
// round-to-nearest-even bf16
__device__ __forceinline__ unsigned int rnd16(float v) {
    unsigned int u = __float_as_uint(v);
    return (u + 0x7FFFu + ((u >> 16) & 1u)) >> 16;
}
__device__ __forceinline__ float bfl(unsigned int u) { return __uint_as_float(u << 16); }
__device__ __forceinline__ float bfh(unsigned int u) { return __uint_as_float(u & 0xFFFF0000u); }

// ====== split-bf16 MFMA GEMM, operands pre-split, k-chunk-major (PROVEN) ======
__global__ __launch_bounds__(256, 4) void gemm_mfma_v2(
    const ushort_t* __restrict__ Ah, const ushort_t* __restrict__ Al,
    const ushort_t* __restrict__ Bh, const ushort_t* __restrict__ Bl,
    const float* __restrict__ bias,
    int M, int K8, int N, int act,
    float* __restrict__ Cf,                                      // fp32 [M][N]
    ushort_t* __restrict__ Ch, ushort_t* __restrict__ Cl,        // split A-layout
    ushort_t* __restrict__ Cb,                                   // plain bf16 [M][N]
    ushort_t* __restrict__ Ca)                                   // plain bf16 A-layout
{
    __shared__ __align__(16) ushort_t lds[12288];
    const int tid = threadIdx.x;
    const int w = tid >> 6, lane = tid & 63;
    const int row0 = blockIdx.y * 64, col0 = blockIdx.x * 128;
    const int nkb = K8 >> 2;
    const int m16 = lane & 15, q = lane >> 4;
    const bool use_al = (Al != nullptr);

    f32x4 acc[4][2] = {};

    for (int kb = 0; kb < nkb; ++kb) {
        const size_t kc = (size_t)(kb * 4 + w);
        const size_t aoff = (kc * MP + row0) * 8 + lane * 8;
        const size_t boff = (kc * N + col0) * 8 + lane * 8;
        gl_lds16(Ah + aoff, &lds[w * 512]);
        if (use_al) gl_lds16(Al + aoff, &lds[2048 + w * 512]);
        gl_lds16(Bh + boff,       &lds[4096 + w * 1024]);
        gl_lds16(Bh + boff + 512, &lds[4096 + w * 1024 + 512]);
        gl_lds16(Bl + boff,       &lds[8192 + w * 1024]);
        gl_lds16(Bl + boff + 512, &lds[8192 + w * 1024 + 512]);
        __syncthreads();

        bf16x8 fah[4], fal[4], fbh[2], fbl[2];
        const int fa = q * 512 + m16 * 8;
        #pragma unroll
        for (int mi = 0; mi < 4; ++mi) {
            fah[mi] = *(const bf16x8*)&lds[fa + mi * 128];
            if (use_al) fal[mi] = *(const bf16x8*)&lds[2048 + fa + mi * 128];
        }
        const int fb = q * 1024 + (w * 32 + m16) * 8;
        #pragma unroll
        for (int ni = 0; ni < 2; ++ni) {
            fbh[ni] = *(const bf16x8*)&lds[4096 + fb + ni * 128];
            fbl[ni] = *(const bf16x8*)&lds[8192 + fb + ni * 128];
        }
        #pragma unroll
        for (int mi = 0; mi < 4; ++mi)
            #pragma unroll
            for (int ni = 0; ni < 2; ++ni) {
                acc[mi][ni] = __builtin_amdgcn_mfma_f32_16x16x32_bf16(fah[mi], fbh[ni], acc[mi][ni], 0, 0, 0);
                acc[mi][ni] = __builtin_amdgcn_mfma_f32_16x16x32_bf16(fah[mi], fbl[ni], acc[mi][ni], 0, 0, 0);
            }
        if (use_al) {
            #pragma unroll
            for (int mi = 0; mi < 4; ++mi)
                #pragma unroll
                for (int ni = 0; ni < 2; ++ni)
                    acc[mi][ni] = __builtin_amdgcn_mfma_f32_16x16x32_bf16(fal[mi], fbh[ni], acc[mi][ni], 0, 0, 0);
        }
        __syncthreads();
    }

    // epilogue: C/D row=(lane>>4)*4+reg, col=lane&15
    #pragma unroll
    for (int ni = 0; ni < 2; ++ni) {
        const int col = col0 + w * 32 + ni * 16 + m16;
        const float bb = bias ? bias[col] : 0.f;
        #pragma unroll
        for (int mi = 0; mi < 4; ++mi) {
            #pragma unroll
            for (int r = 0; r < 4; ++r) {
                const int row = row0 + mi * 16 + q * 4 + r;
                if (row < M) {
                    float v = acc[mi][ni][r] + bb;
                    if (act) v = fmaxf(v, 0.f);
                    if (Cf) Cf[(size_t)row * N + col] = v;
                    if (Cb) Cb[(size_t)row * N + col] = (ushort_t)rnd16(v);
                    const size_t p = (((size_t)(col >> 3)) * MP + row) * 8 + (col & 7);
                    if (Ch) { Ch[p] = (ushort_t)hi16(v); Cl[p] = (ushort_t)lo16(v); }
                    if (Ca) Ca[p] = (ushort_t)rnd16(v);
                }
            }
        }
    }
}

// ====== FUSED node encoder: C = (relu(x@w1+b1))@w2 + b2, h1 never leaves the block ======
// Phase 1: BN=256 (grid.x folded away, A read ONCE), acc1[4][4] holds h1[64][256].
// Phase 2: 4 steps of 64 h1-cols -> LDS as split-bf16 A2; w2 streamed; acc2[4][2].
__global__ __launch_bounds__(256, 3) void enc_fused_kernel(
    const ushort_t* __restrict__ Ah, const ushort_t* __restrict__ Al,   // xh, xl [68][MP][8]
    const ushort_t* __restrict__ B1h, const ushort_t* __restrict__ B1l, // w1 [68][256][8]
    const ushort_t* __restrict__ B2h, const ushort_t* __restrict__ B2l, // w2 [32][128][8]
    const float* __restrict__ b1, const float* __restrict__ b2,
    float* __restrict__ Cf, ushort_t* __restrict__ Ca)                  // xbuf0, x0a
{
    __shared__ __align__(16) ushort_t lds[24576];   // 48 KB
    const int tid = threadIdx.x;
    const int w = tid >> 6, lane = tid & 63;
    const int row0 = blockIdx.x * 64;
    const int m16 = lane & 15, q = lane >> 4;

    // ---------- phase 1 ----------
    // LDS: A1h [4kc][64][8] @0 (2048e) | A1l @2048 | B1h [4kc][256][8] @4096 (8192e) | B1l @12288
    f32x4 acc1[4][4] = {};
    for (int kb = 0; kb < 17; ++kb) {
        const size_t kc = (size_t)(kb * 4 + w);
        const size_t aoff = (kc * MP + row0) * 8 + lane * 8;
        const size_t boff = kc * 2048 + lane * 8;
        gl_lds16(Ah + aoff, &lds[w * 512]);
        gl_lds16(Al + aoff, &lds[2048 + w * 512]);
        #pragma unroll
        for (int u = 0; u < 4; ++u) {
            gl_lds16(B1h + boff + u * 512, &lds[4096 + w * 2048 + u * 512]);
            gl_lds16(B1l + boff + u * 512, &lds[12288 + w * 2048 + u * 512]);
        }
        __syncthreads();

        bf16x8 fah[4], fal[4], fbh[4], fbl[4];
        const int fa = q * 512 + m16 * 8;
        #pragma unroll
        for (int mi = 0; mi < 4; ++mi) {
            fah[mi] = *(const bf16x8*)&lds[fa + mi * 128];
            fal[mi] = *(const bf16x8*)&lds[2048 + fa + mi * 128];
        }
        #pragma unroll
        for (int ni = 0; ni < 4; ++ni) {
            const int fb = q * 2048 + (ni * 64 + w * 16 + m16) * 8;   // col = ni*64 + w*16 + m16
            fbh[ni] = *(const bf16x8*)&lds[4096 + fb];
            fbl[ni] = *(const bf16x8*)&lds[12288 + fb];
        }
        #pragma unroll
        for (int mi = 0; mi < 4; ++mi)
            #pragma unroll
            for (int ni = 0; ni < 4; ++ni) {
                acc1[mi][ni] = __builtin_amdgcn_mfma_f32_16x16x32_bf16(fah[mi], fbh[ni], acc1[mi][ni], 0, 0, 0);
                acc1[mi][ni] = __builtin_amdgcn_mfma_f32_16x16x32_bf16(fah[mi], fbl[ni], acc1[mi][ni], 0, 0, 0);
                acc1[mi][ni] = __builtin_amdgcn_mfma_f32_16x16x32_bf16(fal[mi], fbh[ni], acc1[mi][ni], 0, 0, 0);
            }
        __syncthreads();
    }

    float b1c[4];
    #pragma unroll
    for (int ni = 0; ni < 4; ++ni) b1c[ni] = b1[ni * 64 + w * 16 + m16];

    // ---------- phase 2 ----------
    // LDS: A2h [8kc][64][8] @0 (4096e) | A2l @4096 | B2h [8kc][128][8] @8192 (8192e) | B2l @16384
    f32x4 acc2[4][2] = {};
    const int kc2l = w * 2 + (m16 >> 3);     // local kc of this lane's h1-col
    const int k7 = m16 & 7;
    for (int st = 0; st < 4; ++st) {
        // write this step's 64 h1 cols (relu+bias applied) as split-bf16 A2
        #pragma unroll
        for (int mi = 0; mi < 4; ++mi)
            #pragma unroll
            for (int r = 0; r < 4; ++r) {
                const float v = fmaxf(acc1[mi][st][r] + b1c[st], 0.f);
                const int ad = kc2l * 512 + (mi * 16 + q * 4 + r) * 8 + k7;
                lds[ad] = (ushort_t)hi16(v);
                lds[4096 + ad] = (ushort_t)lo16(v);
            }
        // stage w2 chunk: global kc = st*8 + w*2 + {0,1}
        #pragma unroll
        for (int c = 0; c < 2; ++c) {
            const size_t bo = (size_t)(st * 8 + w * 2 + c) * 1024 + lane * 8;
            const int dl = (w * 2 + c) * 1024;
            gl_lds16(B2h + bo,       &lds[8192 + dl]);
            gl_lds16(B2h + bo + 512, &lds[8192 + dl + 512]);
            gl_lds16(B2l + bo,       &lds[16384 + dl]);
            gl_lds16(B2l + bo + 512, &lds[16384 + dl + 512]);
        }
        __syncthreads();

        #pragma unroll
        for (int kb2 = 0; kb2 < 2; ++kb2) {
            bf16x8 ah[4], al[4], bh[2], bl[2];
            const int fa2 = (kb2 * 4 + q) * 512 + m16 * 8;
            #pragma unroll
            for (int mi = 0; mi < 4; ++mi) {
                ah[mi] = *(const bf16x8*)&lds[fa2 + mi * 128];
                al[mi] = *(const bf16x8*)&lds[4096 + fa2 + mi * 128];
            }
            #pragma unroll
            for (int ni = 0; ni < 2; ++ni) {
                const int fb2 = (kb2 * 4 + q) * 1024 + (w * 32 + ni * 16 + m16) * 8;
                bh[ni] = *(const bf16x8*)&lds[8192 + fb2];
                bl[ni] = *(const bf16x8*)&lds[16384 + fb2];
            }
            #pragma unroll
            for (int mi = 0; mi < 4; ++mi)
                #pragma unroll
                for (int ni = 0; ni < 2; ++ni) {
                    acc2[mi][ni] = __builtin_amdgcn_mfma_f32_16x16x32_bf16(ah[mi], bh[ni], acc2[mi][ni], 0, 0, 0);
                    acc2[mi][ni] = __builtin_amdgcn_mfma_f32_16x16x32_bf16(ah[mi], bl[ni], acc2[mi][ni], 0, 0, 0);
                    acc2[mi][ni] = __builtin_amdgcn_mfma_f32_16x16x32_bf16(al[mi], bh[ni], acc2[mi][ni], 0, 0, 0);
                }
        }
        __syncthreads();
    }

    // epilogue: xbuf0 fp32 [M][128] + x0a bf16 A-layout
    #pragma unroll
    for (int ni = 0; ni < 2; ++ni) {
        const int col = w * 32 + ni * 16 + m16;
        const float bb = b2[col];
        #pragma unroll
        for (int mi = 0; mi < 4; ++mi) {
            #pragma unroll
            for (int r = 0; r < 4; ++r) {
                const int row = row0 + mi * 16 + q * 4 + r;
                if (row < N_NODES) {
                    const float v = acc2[mi][ni][r] + bb;
                    Cf[(size_t)row * DIM + col] = v;
                    const size_t p = (((size_t)(col >> 3)) * MP + row) * 8 + (col & 7);
                    Ca[p] = (ushort_t)rnd16(v);
                }
            }
        }
    }
}

// ---- x fp32 [N_NODES][F_IN] -> xh/xl bf16 [K8][MP][8], coalesced via LDS tile ----
__global__ __launch_bounds__(256) void conv_a_t_kernel(
    const float* __restrict__ x, ushort_t* __restrict__ xh, ushort_t* __restrict__ xl)
{
    __shared__ float tile[64][68];
    const int tid = threadIdx.x;
    const int r0 = blockIdx.x * 64;
    const int c0 = blockIdx.y * 64;

    #pragma unroll
    for (int it = 0; it < 4; ++it) {
        const int r = (tid >> 4) + it * 16;
        const int c = (tid & 15) * 4;
        const int gr = r0 + r, gc = c0 + c;
        float4 v = {0.f, 0.f, 0.f, 0.f};
        if (gr < N_NODES) {
            if (gc + 3 < F_IN) {
                v = *(const float4*)(x + (size_t)gr * F_IN + gc);
            } else {
                float tmp[4] = {0.f, 0.f, 0.f, 0.f};
                #pragma unroll
                for (int u = 0; u < 4; ++u)
                    if (gc + u < F_IN) tmp[u] = x[(size_t)gr * F_IN + gc + u];
                v.x = tmp[0]; v.y = tmp[1]; v.z = tmp[2]; v.w = tmp[3];
            }
        }
        tile[r][c] = v.x; tile[r][c+1] = v.y; tile[r][c+2] = v.z; tile[r][c+3] = v.w;
    }
    __syncthreads();

    const int k8l = tid >> 5;
    const int k8 = (c0 >> 3) + k8l;
    if (k8 >= 68) return;
    const int rr = (tid & 31) * 2;
    #pragma unroll
    for (int u = 0; u < 2; ++u) {
        const int r = rr + u;
        unsigned int hp[4], lp[4];
        #pragma unroll
        for (int i = 0; i < 4; ++i) {
            const float v0 = tile[r][k8l * 8 + 2 * i];
            const float v1 = tile[r][k8l * 8 + 2 * i + 1];
            hp[i] = (hi16(v1) << 16) | hi16(v0);
            lp[i] = (lo16(v1) << 16) | lo16(v0);
        }
        const size_t p = ((size_t)k8 * MP + r0 + r) * 8;
        *(uint4*)(xh + p) = make_uint4(hp[0], hp[1], hp[2], hp[3]);
        *(uint4*)(xl + p) = make_uint4(lp[0], lp[1], lp[2], lp[3]);
    }
}

// ---- all 4 weights fp32 -> bf16 hi/lo [K8][N][8] in ONE launch ----
#define W1_T (68 * 256 * 8)
#define W2_T (32 * 128 * 8)
#define L_T  (16 * 512 * 8)
__global__ __launch_bounds__(256) void conv_w_all_kernel(
    const float* __restrict__ w1, const float* __restrict__ w2,
    const float* __restrict__ l0, const float* __restrict__ l1,
    ushort_t* __restrict__ w1h, ushort_t* __restrict__ w1l,
    ushort_t* __restrict__ w2h, ushort_t* __restrict__ w2l,
    ushort_t* __restrict__ l0h, ushort_t* __restrict__ l0l,
    ushort_t* __restrict__ l1h, ushort_t* __restrict__ l1l)
{
    int idx = blockIdx.x * 256 + threadIdx.x;
    const float* w; ushort_t *bh, *bl; int K, N, local;
    if (idx < W1_T) { w = w1; bh = w1h; bl = w1l; K = F_IN; N = HIDDEN; local = idx; }
    else if (idx < W1_T + W2_T) { w = w2; bh = w2h; bl = w2l; K = HIDDEN; N = DIM; local = idx - W1_T; }
    else if (idx < W1_T + W2_T + L_T) { w = l0; bh = l0h; bl = l0l; K = DIM; N = 512; local = idx - W1_T - W2_T; }
    else if (idx < W1_T + W2_T + 2 * L_T) { w = l1; bh = l1h; bl = l1l; K = DIM; N = 512; local = idx - W1_T - W2_T - L_T; }
    else return;
    const int j = local & 7;
    const int rem = local >> 3;
    const int n = rem % N;
    const int k = (rem / N) * 8 + j;
    const float v = (k < K) ? w[(size_t)k * N + n] : 0.f;
    bh[local] = (ushort_t)hi16(v);
    bl[local] = (ushort_t)lo16(v);
}

// ---- wa for BOTH layers in one launch ----
__global__ __launch_bounds__(256) void wa2_kernel(
    const float* __restrict__ lin0, const float* __restrict__ lin1,
    const float* __restrict__ atts0, const float* __restrict__ attd0,
    const float* __restrict__ atts1, const float* __restrict__ attd1,
    float* __restrict__ wa_s0, float* __restrict__ wa_d0,
    float* __restrict__ wa_s1, float* __restrict__ wa_d1)
{
    const int wrk = blockIdx.x * 256 + threadIdx.x;
    if (wrk >= 2048) return;
    const int L = wrk >> 10;
    const int sd = (wrk >> 9) & 1;
    const int p = wrk & 511;
    const int h = p >> 7, d = p & 127;
    const float* lin = L ? lin1 : lin0;
    const float* av = L ? (sd ? attd1 : atts1) : (sd ? attd0 : atts0);
    float* out = L ? (sd ? wa_d1 : wa_s1) : (sd ? wa_d0 : wa_s0);
    const float* lp = lin + (size_t)d * (NH * DIM) + h * DIM;
    const float* ap = av + h * DIM;
    float acc = 0.f;
    #pragma unroll 8
    for (int i = 0; i < DIM; ++i) acc += lp[i] * ap[i];
    out[h * DIM + d] = acc;
}

// ---- a_s[n,h], a_d[n,h] from xbuf (fp32 [N][128]) ----
__global__ __launch_bounds__(256) void as_ad_kernel(
    const float* __restrict__ xb, const float* __restrict__ wa_s,
    const float* __restrict__ wa_d, float* __restrict__ a_s, float* __restrict__ a_d)
{
    const int gw = blockIdx.x * 4 + (threadIdx.x >> 6);
    const int lane = threadIdx.x & 63;
    if (gw >= N_NODES * NH) return;
    const int n = gw >> 2, h = gw & 3;
    const float* hp = xb + (size_t)n * DIM;
    float2 hv = *(const float2*)(hp + lane * 2);
    float2 sv = *(const float2*)(wa_s + h * DIM + lane * 2);
    float2 dv = *(const float2*)(wa_d + h * DIM + lane * 2);
    float s = hv.x * sv.x + hv.y * sv.y;
    float d = hv.x * dv.x + hv.y * dv.y;
    #pragma unroll
    for (int off = 32; off > 0; off >>= 1) {
        s += __shfl_down(s, off);
        d += __shfl_down(d, off);
    }
    if (lane == 0) { a_s[n * 4 + h] = s; a_d[n * 4 + h] = d; }
}

// ---- rel attention tables for BOTH layers: blockIdx.x = layer ----
__global__ __launch_bounds__(128) void rel_table2_kernel(
    const float* __restrict__ rel_emb,
    const float* __restrict__ line0, const float* __restrict__ atte0,
    const float* __restrict__ line1, const float* __restrict__ atte1,
    float* __restrict__ table)          // [2][128]
{
    __shared__ float we[32][NH];
    const int L = blockIdx.x;
    const float* line = L ? line1 : line0;
    const float* atte = L ? atte1 : atte0;
    float* tab = table + L * 128;
    const int tid = threadIdx.x;
    const int k = tid >> 2, h = tid & 3;
    float acc = 0.f;
    for (int d = 0; d < DIM; ++d)
        acc += line[(size_t)k * (NH * DIM) + h * DIM + d] * atte[h * DIM + d];
    we[k][h] = acc;
    __syncthreads();
    if (tid < 26 * NH) {
        int r = tid >> 2, hh = tid & 3;
        float t = 0.f;
        for (int kk = 0; kk < 32; ++kk) t += rel_emb[r * 32 + kk] * we[kk][hh];
        tab[r * 4 + hh] = t;
    }
}

// ================= CSR build =================
__global__ __launch_bounds__(256) void hist_kernel(
    const int* __restrict__ dst, int* __restrict__ cnt)
{
    const int e = blockIdx.x * blockDim.x + threadIdx.x;
    if (e >= N_EDGES) return;
    atomicAdd(&cnt[dst[e]], 1);
}

__global__ __launch_bounds__(1024) void scan_kernel(
    const int* __restrict__ cnt, int* __restrict__ ptr, int* __restrict__ ptr_copy)
{
    __shared__ int tsum[1024];
    const int tid = threadIdx.x;
    const int CH = 20;
    const int base = tid * CH;
    int s = 0;
    #pragma unroll
    for (int i = 0; i < CH; ++i) {
        int idx = base + i;
        if (idx < N_NODES) s += cnt[idx];
    }
    tsum[tid] = s;
    __syncthreads();
    for (int off = 1; off < 1024; off <<= 1) {
        int v = (tid >= off) ? tsum[tid - off] : 0;
        __syncthreads();
        tsum[tid] += v;
        __syncthreads();
    }
    int run = (tid == 0) ? 0 : tsum[tid - 1];
    #pragma unroll
    for (int i = 0; i < CH; ++i) {
        int idx = base + i;
        if (idx < N_NODES) {
            ptr[idx] = run;
            ptr_copy[idx] = run;
            run += cnt[idx];
        }
    }
    if (tid == 0) ptr[N_NODES] = N_EDGES;
}

__global__ __launch_bounds__(256) void scatter_kernel(
    const int* __restrict__ src, const int* __restrict__ dst, const int* __restrict__ etype,
    int* __restrict__ ptr_copy, int2* __restrict__ se, int* __restrict__ dcsr)
{
    const int e = blockIdx.x * blockDim.x + threadIdx.x;
    if (e >= N_EDGES) return;
    const int d = dst[e];
    const int pos = atomicAdd(&ptr_copy[d], 1);
    se[pos] = make_int2(src[e], etype[e]);
    dcsr[pos] = d;
}

// ======== per-edge softmax numerator p[j][h], CSR-ordered, fully coalesced ========
__global__ __launch_bounds__(256) void edge_p_kernel(
    const int2* __restrict__ se, const int* __restrict__ dcsr,
    const float* __restrict__ a_s, const float* __restrict__ a_d,
    const float* __restrict__ table, float* __restrict__ p4)
{
    const int j0 = (blockIdx.x * 256 + threadIdx.x) * 2;
    const int2 eA = se[j0], eB = se[j0 + 1];
    const int dA = dcsr[j0], dB = dcsr[j0 + 1];
    const float4 asA = *(const float4*)(a_s + eA.x * 4);
    const float4 asB = *(const float4*)(a_s + eB.x * 4);
    const float4 adA = *(const float4*)(a_d + dA * 4);
    const float4 adB = *(const float4*)(a_d + dB * 4);
    const float4 tA  = *(const float4*)(table + eA.y * 4);
    const float4 tB  = *(const float4*)(table + eB.y * 4);
    float4 oA, oB;
    oA.x = __expf(lrelu02(asA.x + adA.x + tA.x));
    oA.y = __expf(lrelu02(asA.y + adA.y + tA.y));
    oA.z = __expf(lrelu02(asA.z + adA.z + tA.z));
    oA.w = __expf(lrelu02(asA.w + adA.w + tA.w));
    oB.x = __expf(lrelu02(asB.x + adB.x + tB.x));
    oB.y = __expf(lrelu02(asB.y + adB.y + tB.y));
    oB.z = __expf(lrelu02(asB.z + adB.z + tB.z));
    oB.w = __expf(lrelu02(asB.w + adB.w + tB.w));
    *(float4*)(p4 + (size_t)j0 * 4)     = oA;
    *(float4*)(p4 + (size_t)j0 * 4 + 4) = oB;
}

// ======== shared edge-loop body: weighted gather + eh table-sum ========
__device__ __forceinline__ void acc8(float acc[8], float p, const uint4 g)
{
    acc[0] += p * bfl(g.x); acc[1] += p * bfh(g.x);
    acc[2] += p * bfl(g.y); acc[3] += p * bfh(g.y);
    acc[4] += p * bfl(g.z); acc[5] += p * bfh(g.z);
    acc[6] += p * bfl(g.w); acc[7] += p * bfh(g.w);
}

__device__ __forceinline__ void agg_loop(
    int beg, int end, int n, int head, int cbase,
    const int2* __restrict__ se, const float* __restrict__ p4,
    const float* __restrict__ table, const float* __restrict__ a_s, float adh,
    const ushort_t* __restrict__ hb, float acc[8], float& dh)
{
    // self-loop row: issue early so its latency hides under the edge loop
    const uint4 gs = *(const uint4*)(hb + (size_t)n * 512 + cbase);

    float eh = 0.f;
    int j = beg;
    for (; j + 4 <= end; j += 4) {
        const int2 e0 = se[j],     e1 = se[j + 1];
        const int2 e2 = se[j + 2], e3 = se[j + 3];
        const float* pj = p4 + ((size_t)j * 4 + head);
        const float p0 = pj[0], p1 = pj[4], p2 = pj[8], p3 = pj[12];
        const uint4 g0 = *(const uint4*)(hb + (size_t)e0.x * 512 + cbase);
        const uint4 g1 = *(const uint4*)(hb + (size_t)e1.x * 512 + cbase);
        const uint4 g2 = *(const uint4*)(hb + (size_t)e2.x * 512 + cbase);
        const uint4 g3 = *(const uint4*)(hb + (size_t)e3.x * 512 + cbase);
        eh += (table[e0.y * 4 + head] + table[e1.y * 4 + head])
            + (table[e2.y * 4 + head] + table[e3.y * 4 + head]);
        dh += (p0 + p1) + (p2 + p3);
        acc8(acc, p0, g0); acc8(acc, p1, g1);
        acc8(acc, p2, g2); acc8(acc, p3, g3);
    }
    for (; j + 2 <= end; j += 2) {
        const int2 e0 = se[j], e1 = se[j + 1];
        const float* pj = p4 + ((size_t)j * 4 + head);
        const float p0 = pj[0], p1 = pj[4];
        const uint4 g0 = *(const uint4*)(hb + (size_t)e0.x * 512 + cbase);
        const uint4 g1 = *(const uint4*)(hb + (size_t)e1.x * 512 + cbase);
        eh += table[e0.y * 4 + head] + table[e1.y * 4 + head];
        dh += p0 + p1;
        acc8(acc, p0, g0); acc8(acc, p1, g1);
    }
    if (j < end) {
        const int2 e0 = se[j];
        const float p0 = p4[(size_t)j * 4 + head];
        const uint4 g0 = *(const uint4*)(hb + (size_t)e0.x * 512 + cbase);
        eh += table[e0.y * 4 + head];
        dh += p0;
        acc8(acc, p0, g0);
    }
    // self-loop (fill_value='mean')
    const float inv = 1.0f / fmaxf((float)(end - beg), 1.0f);
    const float ps = __expf(lrelu02(a_s[n * 4 + head] + adh + eh * inv));
    dh += ps;
    acc8(acc, ps, gs);
}

// ===== L0 variant: bf16 A-layout out + FUSED next-layer a_s/a_d =====
__global__ __launch_bounds__(256) void node_agg_f_kernel(
    const int* __restrict__ ptr, const int2* __restrict__ se,
    const float* __restrict__ p4, const float* __restrict__ table,
    const float* __restrict__ a_s, const float* __restrict__ a_d,
    const ushort_t* __restrict__ hb,
    const float* __restrict__ bias, ushort_t* __restrict__ oa,
    const float* __restrict__ wa_s2, const float* __restrict__ wa_d2,
    float* __restrict__ a_s2, float* __restrict__ a_d2)
{
    const int n = blockIdx.x * 4 + (threadIdx.x >> 6);
    const int lane = threadIdx.x & 63;
    if (n >= N_NODES) return;
    const int beg = ptr[n], end = ptr[n + 1];
    const int head = lane >> 4;
    const int cbase = lane * 8;
    const float adh = a_d[n * 4 + head];

    float acc[8] = {};
    float dh = 0.f;
    agg_loop(beg, end, n, head, cbase, se, p4, table, a_s, adh, hb, acc, dh);

    const float ih = 0.25f / (dh + 1e-16f);
    float t[8];
    #pragma unroll
    for (int k = 0; k < 8; ++k) {
        t[k] = acc[k] * ih;
        t[k] += __shfl_xor(t[k], 16);
        t[k] += __shfl_xor(t[k], 32);
    }
    if (lane < 16) {
        const float4 b0 = *(const float4*)(bias + cbase);
        const float4 b1 = *(const float4*)(bias + cbase + 4);
        float o[8];
        o[0] = fmaxf(t[0] + b0.x, 0.f); o[1] = fmaxf(t[1] + b0.y, 0.f);
        o[2] = fmaxf(t[2] + b0.z, 0.f); o[3] = fmaxf(t[3] + b0.w, 0.f);
        o[4] = fmaxf(t[4] + b1.x, 0.f); o[5] = fmaxf(t[5] + b1.y, 0.f);
        o[6] = fmaxf(t[6] + b1.z, 0.f); o[7] = fmaxf(t[7] + b1.w, 0.f);
        unsigned int up[4];
        #pragma unroll
        for (int i = 0; i < 4; ++i)
            up[i] = (rnd16(o[2*i+1]) << 16) | rnd16(o[2*i]);
        *(uint4*)(oa + ((size_t)lane * MP + n) * 8) = make_uint4(up[0], up[1], up[2], up[3]);
        // fused next-layer a_s/a_d: per-head 128-dot over the output row
        float pss[4] = {0,0,0,0}, pdd[4] = {0,0,0,0};
        #pragma unroll
        for (int h = 0; h < NH; ++h) {
            const float* ws = wa_s2 + h * DIM + cbase;
            const float* wd = wa_d2 + h * DIM + cbase;
            #pragma unroll
            for (int i = 0; i < 8; ++i) {
                pss[h] += o[i] * ws[i];
                pdd[h] += o[i] * wd[i];
            }
        }
        #pragma unroll
        for (int m = 1; m < 16; m <<= 1) {
            #pragma unroll
            for (int h = 0; h < NH; ++h) {
                pss[h] += __shfl_xor(pss[h], m);
                pdd[h] += __shfl_xor(pdd[h], m);
            }
        }
        if (lane == 0) {
            float4 vs = {pss[0], pss[1], pss[2], pss[3]};
            float4 vd = {pdd[0], pdd[1], pdd[2], pdd[3]};
            *(float4*)(a_s2 + n * 4) = vs;
            *(float4*)(a_d2 + n * 4) = vd;
        }
    }
}

// ===== L1 variant: fp32 out only, no fusion =====
__global__ __launch_bounds__(256) void node_agg_s_kernel(
    const int* __restrict__ ptr, const int2* __restrict__ se,
    const float* __restrict__ p4, const float* __restrict__ table,
    const float* __restrict__ a_s, const float* __restrict__ a_d,
    const ushort_t* __restrict__ hb,
    const float* __restrict__ bias, float* __restrict__ outf)
{
    const int n = blockIdx.x * 4 + (threadIdx.x >> 6);
    const int lane = threadIdx.x & 63;
    if (n >= N_NODES) return;
    const int beg = ptr[n], end = ptr[n + 1];
    const int head = lane >> 4;
    const int cbase = lane * 8;
    const float adh = a_d[n * 4 + head];

    float acc[8] = {};
    float dh = 0.f;
    agg_loop(beg, end, n, head, cbase, se, p4, table, a_s, adh, hb, acc, dh);

    const float ih = 0.25f / (dh + 1e-16f);
    float t[8];
    #pragma unroll
    for (int k = 0; k < 8; ++k) {
        t[k] = acc[k] * ih;
        t[k] += __shfl_xor(t[k], 16);
        t[k] += __shfl_xor(t[k], 32);
    }
    if (lane < 16) {
        const float4 b0 = *(const float4*)(bias + cbase);
        const float4 b1 = *(const float4*)(bias + cbase + 4);
        float4 v0, v1;
        v0.x = fmaxf(t[0] + b0.x, 0.f); v0.y = fmaxf(t[1] + b0.y, 0.f);
        v0.z = fmaxf(t[2] + b0.z, 0.f); v0.w = fmaxf(t[3] + b0.w, 0.f);
        v1.x = fmaxf(t[4] + b1.x, 0.f); v1.y = fmaxf(t[5] + b1.y, 0.f);
        v1.z = fmaxf(t[6] + b1.z, 0.f); v1.w = fmaxf(t[7] + b1.w, 0.f);
        *(float4*)(outf + (size_t)n * DIM + cbase) = v0;
        *(float4*)(outf + (size_t)n * DIM + cbase + 4) = v1;
    }
}

extern "C" void kernel_launch(void* const* d_in, const int* in_sizes, int n_in,
                              void* d_out, int out_size, void* d_ws, size_t ws_size,
                              hipStream_t stream)
{
    const float* x       = (const float*)d_in[0];
    const int*   eidx    = (const int*)d_in[1];
    const int*   etype   = (const int*)d_in[2];
    const float* w1      = (const float*)d_in[3];
    const float* b1      = (const float*)d_in[4];
    const float* w2      = (const float*)d_in[5];
    const float* b2      = (const float*)d_in[6];
    const float* rel_emb = (const float*)d_in[7];
    const float* lin[2]  = {(const float*)d_in[8],  (const float*)d_in[14]};
    const float* line[2] = {(const float*)d_in[9],  (const float*)d_in[15]};
    const float* atts[2] = {(const float*)d_in[10], (const float*)d_in[16]};
    const float* attd[2] = {(const float*)d_in[11], (const float*)d_in[17]};
    const float* atte[2] = {(const float*)d_in[12], (const float*)d_in[18]};
    const float* bias[2] = {(const float*)d_in[13], (const float*)d_in[19]};
    const int* src = eidx;
    const int* dst = eidx + N_EDGES;

    // ---- workspace layout ----
    char* base = (char*)d_ws;
    size_t off = 0;
    auto alloc = [&](size_t bytes) -> void* {
        void* p = base + off;
        off = (off + bytes + 255) & ~(size_t)255;
        return p;
    };
    ushort_t* xh  = (ushort_t*)alloc((size_t)68 * MP * 8 * 2);  // hb overlays (dead after enc)
    ushort_t* xl  = (ushort_t*)alloc((size_t)68 * MP * 8 * 2);
    ushort_t* x0a = (ushort_t*)alloc((size_t)16 * MP * 8 * 2);
    void* reg1    = alloc((size_t)16 * MP * 8 * 4);             // xbuf0 fp32 | x1a
    ushort_t* w1h = (ushort_t*)alloc(W1_T * 2);
    ushort_t* w1l = (ushort_t*)alloc(W1_T * 2);
    ushort_t* w2h = (ushort_t*)alloc(W2_T * 2);
    ushort_t* w2l = (ushort_t*)alloc(W2_T * 2);
    ushort_t* l0h = (ushort_t*)alloc(L_T * 2);
    ushort_t* l0l = (ushort_t*)alloc(L_T * 2);
    ushort_t* l1h = (ushort_t*)alloc(L_T * 2);
    ushort_t* l1l = (ushort_t*)alloc(L_T * 2);
    float* a_s0  = (float*)alloc(N_NODES * 4 * 4);
    float* a_d0  = (float*)alloc(N_NODES * 4 * 4);
    float* a_s1  = (float*)alloc(N_NODES * 4 * 4);
    float* a_d1  = (float*)alloc(N_NODES * 4 * 4);
    float* table = (float*)alloc(2 * 128 * 4);
    float* wa_s0 = (float*)alloc(512 * 4);
    float* wa_d0 = (float*)alloc(512 * 4);
    float* wa_s1 = (float*)alloc(512 * 4);
    float* wa_d1 = (float*)alloc(512 * 4);
    int*  cnt_i  = (int*)alloc(N_NODES * 4);
    int*  ptr    = (int*)alloc((N_NODES + 4) * 4);
    int*  ptrc   = (int*)alloc(N_NODES * 4);
    int2* se     = (int2*)alloc((size_t)N_EDGES * 8);
    int*  dcsr   = (int*)alloc((size_t)N_EDGES * 4);            // CSR pos -> dst node
    float* p4    = (float*)alloc((size_t)N_EDGES * 4 * 4);      // per-edge p (layer-reused)

    ushort_t* hb = xh;              // bf16 hfeat [MP][512], 20.5 MB (xh dead after enc)
    float* xbuf0 = (float*)reg1;
    ushort_t* x1a = (ushort_t*)reg1;  // node_agg L0 bf16 A-layout out (xbuf0 dead after as_ad L0)

    const int mtiles = MP / 64;     // 313
    const int ep_grid = N_EDGES / 512;   // 625, exact

    // ---- input conversions (merged launches) ----
    conv_a_t_kernel<<<dim3(MP / 64, 9), 256, 0, stream>>>(x, xh, xl);
    conv_w_all_kernel<<<(W1_T + W2_T + 2 * L_T + 255) / 256, 256, 0, stream>>>(
        w1, w2, lin[0], lin[1], w1h, w1l, w2h, w2l, l0h, l0l, l1h, l1l);
    wa2_kernel<<<8, 256, 0, stream>>>(lin[0], lin[1], atts[0], attd[0], atts[1], attd[1],
                                      wa_s0, wa_d0, wa_s1, wa_d1);
    rel_table2_kernel<<<2, 128, 0, stream>>>(rel_emb, line[0], atte[0], line[1], atte[1], table);

    // ---- CSR build ----
    hipMemsetAsync(cnt_i, 0, N_NODES * sizeof(int), stream);
    hist_kernel<<<(N_EDGES + 255) / 256, 256, 0, stream>>>(dst, cnt_i);
    scan_kernel<<<1, 1024, 0, stream>>>(cnt_i, ptr, ptrc);
    scatter_kernel<<<(N_EDGES + 255) / 256, 256, 0, stream>>>(src, dst, etype, ptrc, se, dcsr);

    // ---- FUSED node encoder (h1 never hits HBM) ----
    enc_fused_kernel<<<mtiles, 256, 0, stream>>>(
        xh, xl, w1h, w1l, w2h, w2l, b1, b2, xbuf0, x0a);

    // ---- layer 0 (2-term: A quantized bf16) ----
    gemm_mfma_v2<<<dim3((NH * DIM) / 128, mtiles), 256, 0, stream>>>(
        x0a, nullptr, l0h, l0l, nullptr, N_NODES, 16, NH * DIM, 0, nullptr, nullptr, nullptr, hb, nullptr);
    as_ad_kernel<<<N_NODES, 256, 0, stream>>>(xbuf0, wa_s0, wa_d0, a_s0, a_d0);
    edge_p_kernel<<<ep_grid, 256, 0, stream>>>(se, dcsr, a_s0, a_d0, table, p4);
    node_agg_f_kernel<<<(N_NODES + 3) / 4, 256, 0, stream>>>(
        ptr, se, p4, table, a_s0, a_d0, hb, bias[0], x1a,
        wa_s1, wa_d1, a_s1, a_d1);

    // ---- layer 1 (2-term; a_s/a_d computed by node_agg L0) ----
    gemm_mfma_v2<<<dim3((NH * DIM) / 128, mtiles), 256, 0, stream>>>(
        x1a, nullptr, l1h, l1l, nullptr, N_NODES, 16, NH * DIM, 0, nullptr, nullptr, nullptr, hb, nullptr);
    edge_p_kernel<<<ep_grid, 256, 0, stream>>>(se, dcsr, a_s1, a_d1, table + 128, p4);
    node_agg_s_kernel<<<(N_NODES + 3) / 4, 256, 0, stream>>>(
        ptr, se, p4, table + 128, a_s1, a_d1, hb, bias[1], (float*)d_out);
}

// Round 6
// 403.357 us; speedup vs baseline: 1.0817x; 1.0237x over previous
//
#include <hip/hip_runtime.h>
#include <math.h>

#define N_NODES 20000
#define MP      20032          // M padded to 64
#define N_EDGES 320000
#define F_IN    518
#define HIDDEN  256
#define DIM     128
#define NH      4

typedef __attribute__((ext_vector_type(8))) short bf16x8;
typedef __attribute__((ext_vector_type(4))) float f32x4;
typedef unsigned short ushort_t;

__device__ __forceinline__ float lrelu02(float x) { return x > 0.f ? x : 0.2f * x; }

__device__ __forceinline__ void gl_lds16(const void* g, void* l) {
    __builtin_amdgcn_global_load_lds(
        (const __attribute__((address_space(1))) unsigned int*)g,
        (__attribute__((address_space(3))) unsigned int*)l, 16, 0, 0);
}

__device__ __forceinline__ unsigned int hi16(float v) { return __float_as_uint(v) >> 16; }
__device__ __forceinline__ unsigned int lo16(float v) {
    unsigned int h = __float_as_uint(v) & 0xFFFF0000u;
    return __float_as_uint(v - __uint_as_float(h)) >> 16;
}
// round-to-nearest-even bf16
__device__ __forceinline__ unsigned int rnd16(float v) {
    unsigned int u = __float_as_uint(v);
    return (u + 0x7FFFu + ((u >> 16) & 1u)) >> 16;
}
__device__ __forceinline__ float bfl(unsigned int u) { return __uint_as_float(u << 16); }
__device__ __forceinline__ float bfh(unsigned int u) { return __uint_as_float(u & 0xFFFF0000u); }

// ====== split-bf16 MFMA GEMM, operands pre-split, k-chunk-major (PROVEN) ======
__global__ __launch_bounds__(256, 4) void gemm_mfma_v2(
    const ushort_t* __restrict__ Ah, const ushort_t* __restrict__ Al,
    const ushort_t* __restrict__ Bh, const ushort_t* __restrict__ Bl,
    const float* __restrict__ bias,
    int M, int K8, int N, int act,
    float* __restrict__ Cf,                                      // fp32 [M][N]
    ushort_t* __restrict__ Ch, ushort_t* __restrict__ Cl,        // split A-layout
    ushort_t* __restrict__ Cb,                                   // plain bf16 [M][N]
    ushort_t* __restrict__ Ca)                                   // plain bf16 A-layout
{
    __shared__ __align__(16) ushort_t lds[12288];
    const int tid = threadIdx.x;
    const int w = tid >> 6, lane = tid & 63;
    const int row0 = blockIdx.y * 64, col0 = blockIdx.x * 128;
    const int nkb = K8 >> 2;
    const int m16 = lane & 15, q = lane >> 4;
    const bool use_al = (Al != nullptr);

    f32x4 acc[4][2] = {};

    for (int kb = 0; kb < nkb; ++kb) {
        const size_t kc = (size_t)(kb * 4 + w);
        const size_t aoff = (kc * MP + row0) * 8 + lane * 8;
        const size_t boff = (kc * N + col0) * 8 + lane * 8;
        gl_lds16(Ah + aoff, &lds[w * 512]);
        if (use_al) gl_lds16(Al + aoff, &lds[2048 + w * 512]);
        gl_lds16(Bh + boff,       &lds[4096 + w * 1024]);
        gl_lds16(Bh + boff + 512, &lds[4096 + w * 1024 + 512]);
        gl_lds16(Bl + boff,       &lds[8192 + w * 1024]);
        gl_lds16(Bl + boff + 512, &lds[8192 + w * 1024 + 512]);
        __syncthreads();

        bf16x8 fah[4], fal[4], fbh[2], fbl[2];
        const int fa = q * 512 + m16 * 8;
        #pragma unroll
        for (int mi = 0; mi < 4; ++mi) {
            fah[mi] = *(const bf16x8*)&lds[fa + mi * 128];
            if (use_al) fal[mi] = *(const bf16x8*)&lds[2048 + fa + mi * 128];
        }
        const int fb = q * 1024 + (w * 32 + m16) * 8;
        #pragma unroll
        for (int ni = 0; ni < 2; ++ni) {
            fbh[ni] = *(const bf16x8*)&lds[4096 + fb + ni * 128];
            fbl[ni] = *(const bf16x8*)&lds[8192 + fb + ni * 128];
        }
        #pragma unroll
        for (int mi = 0; mi < 4; ++mi)
            #pragma unroll
            for (int ni = 0; ni < 2; ++ni) {
                acc[mi][ni] = __builtin_amdgcn_mfma_f32_16x16x32_bf16(fah[mi], fbh[ni], acc[mi][ni], 0, 0, 0);
                acc[mi][ni] = __builtin_amdgcn_mfma_f32_16x16x32_bf16(fah[mi], fbl[ni], acc[mi][ni], 0, 0, 0);
            }
        if (use_al) {
            #pragma unroll
            for (int mi = 0; mi < 4; ++mi)
                #pragma unroll
                for (int ni = 0; ni < 2; ++ni)
                    acc[mi][ni] = __builtin_amdgcn_mfma_f32_16x16x32_bf16(fal[mi], fbh[ni], acc[mi][ni], 0, 0, 0);
        }
        __syncthreads();
    }

    // epilogue: C/D row=(lane>>4)*4+reg, col=lane&15
    #pragma unroll
    for (int ni = 0; ni < 2; ++ni) {
        const int col = col0 + w * 32 + ni * 16 + m16;
        const float bb = bias ? bias[col] : 0.f;
        #pragma unroll
        for (int mi = 0; mi < 4; ++mi) {
            #pragma unroll
            for (int r = 0; r < 4; ++r) {
                const int row = row0 + mi * 16 + q * 4 + r;
                if (row < M) {
                    float v = acc[mi][ni][r] + bb;
                    if (act) v = fmaxf(v, 0.f);
                    if (Cf) Cf[(size_t)row * N + col] = v;
                    if (Cb) Cb[(size_t)row * N + col] = (ushort_t)rnd16(v);
                    const size_t p = (((size_t)(col >> 3)) * MP + row) * 8 + (col & 7);
                    if (Ch) { Ch[p] = (ushort_t)hi16(v); Cl[p] = (ushort_t)lo16(v); }
                    if (Ca) Ca[p] = (ushort_t)rnd16(v);
                }
            }
        }
    }
}

// ====== FUSED node encoder + L0 GAT lin: ======
// Phase 1: h1 = relu(x@w1+b1) in regs (BN=256, A read once).  Phase 2: x0 = h1@w2+b2.
// Phase 3: hb0 = rnd16(x0) @ l0  (2-term split B), written to DEDICATED buffer.
__global__ __launch_bounds__(256, 2) void enc_fused_kernel(
    const ushort_t* __restrict__ Ah, const ushort_t* __restrict__ Al,   // xh, xl [68][MP][8]
    const ushort_t* __restrict__ B1h, const ushort_t* __restrict__ B1l, // w1 [68][256][8]
    const ushort_t* __restrict__ B2h, const ushort_t* __restrict__ B2l, // w2 [32][128][8]
    const ushort_t* __restrict__ B3h, const ushort_t* __restrict__ B3l, // l0 [16][512][8]
    const float* __restrict__ b1, const float* __restrict__ b2,
    float* __restrict__ Cf, ushort_t* __restrict__ hbout)               // xbuf0, hb0
{
    __shared__ __align__(16) ushort_t lds[24576];   // 48 KB
    const int tid = threadIdx.x;
    const int w = tid >> 6, lane = tid & 63;
    const int row0 = blockIdx.x * 64;
    const int m16 = lane & 15, q = lane >> 4;

    // ---------- phase 1 ----------
    // LDS: A1h [4kc][64][8] @0 | A1l @2048 | B1h [4kc][256][8] @4096 | B1l @12288
    f32x4 acc1[4][4] = {};
    for (int kb = 0; kb < 17; ++kb) {
        const size_t kc = (size_t)(kb * 4 + w);
        const size_t aoff = (kc * MP + row0) * 8 + lane * 8;
        const size_t boff = kc * 2048 + lane * 8;
        gl_lds16(Ah + aoff, &lds[w * 512]);
        gl_lds16(Al + aoff, &lds[2048 + w * 512]);
        #pragma unroll
        for (int u = 0; u < 4; ++u) {
            gl_lds16(B1h + boff + u * 512, &lds[4096 + w * 2048 + u * 512]);
            gl_lds16(B1l + boff + u * 512, &lds[12288 + w * 2048 + u * 512]);
        }
        __syncthreads();

        bf16x8 fah[4], fal[4], fbh[4], fbl[4];
        const int fa = q * 512 + m16 * 8;
        #pragma unroll
        for (int mi = 0; mi < 4; ++mi) {
            fah[mi] = *(const bf16x8*)&lds[fa + mi * 128];
            fal[mi] = *(const bf16x8*)&lds[2048 + fa + mi * 128];
        }
        #pragma unroll
        for (int ni = 0; ni < 4; ++ni) {
            const int fb = q * 2048 + (ni * 64 + w * 16 + m16) * 8;
            fbh[ni] = *(const bf16x8*)&lds[4096 + fb];
            fbl[ni] = *(const bf16x8*)&lds[12288 + fb];
        }
        #pragma unroll
        for (int mi = 0; mi < 4; ++mi)
            #pragma unroll
            for (int ni = 0; ni < 4; ++ni) {
                acc1[mi][ni] = __builtin_amdgcn_mfma_f32_16x16x32_bf16(fah[mi], fbh[ni], acc1[mi][ni], 0, 0, 0);
                acc1[mi][ni] = __builtin_amdgcn_mfma_f32_16x16x32_bf16(fah[mi], fbl[ni], acc1[mi][ni], 0, 0, 0);
                acc1[mi][ni] = __builtin_amdgcn_mfma_f32_16x16x32_bf16(fal[mi], fbh[ni], acc1[mi][ni], 0, 0, 0);
            }
        __syncthreads();
    }

    float b1c[4];
    #pragma unroll
    for (int ni = 0; ni < 4; ++ni) b1c[ni] = b1[ni * 64 + w * 16 + m16];

    // ---------- phase 2 ----------
    // LDS: A2h [8kc][64][8] @0 | A2l @4096 | B2h [8kc][128][8] @8192 | B2l @16384
    f32x4 acc2[4][2] = {};
    const int kc2l = w * 2 + (m16 >> 3);
    const int k7 = m16 & 7;
    for (int st = 0; st < 4; ++st) {
        #pragma unroll
        for (int mi = 0; mi < 4; ++mi)
            #pragma unroll
            for (int r = 0; r < 4; ++r) {
                const float v = fmaxf(acc1[mi][st][r] + b1c[st], 0.f);
                const int ad = kc2l * 512 + (mi * 16 + q * 4 + r) * 8 + k7;
                lds[ad] = (ushort_t)hi16(v);
                lds[4096 + ad] = (ushort_t)lo16(v);
            }
        #pragma unroll
        for (int c = 0; c < 2; ++c) {
            const size_t bo = (size_t)(st * 8 + w * 2 + c) * 1024 + lane * 8;
            const int dl = (w * 2 + c) * 1024;
            gl_lds16(B2h + bo,       &lds[8192 + dl]);
            gl_lds16(B2h + bo + 512, &lds[8192 + dl + 512]);
            gl_lds16(B2l + bo,       &lds[16384 + dl]);
            gl_lds16(B2l + bo + 512, &lds[16384 + dl + 512]);
        }
        __syncthreads();

        #pragma unroll
        for (int kb2 = 0; kb2 < 2; ++kb2) {
            bf16x8 ah[4], al[4], bh[2], bl[2];
            const int fa2 = (kb2 * 4 + q) * 512 + m16 * 8;
            #pragma unroll
            for (int mi = 0; mi < 4; ++mi) {
                ah[mi] = *(const bf16x8*)&lds[fa2 + mi * 128];
                al[mi] = *(const bf16x8*)&lds[4096 + fa2 + mi * 128];
            }
            #pragma unroll
            for (int ni = 0; ni < 2; ++ni) {
                const int fb2 = (kb2 * 4 + q) * 1024 + (w * 32 + ni * 16 + m16) * 8;
                bh[ni] = *(const bf16x8*)&lds[8192 + fb2];
                bl[ni] = *(const bf16x8*)&lds[16384 + fb2];
            }
            #pragma unroll
            for (int mi = 0; mi < 4; ++mi)
                #pragma unroll
                for (int ni = 0; ni < 2; ++ni) {
                    acc2[mi][ni] = __builtin_amdgcn_mfma_f32_16x16x32_bf16(ah[mi], bh[ni], acc2[mi][ni], 0, 0, 0);
                    acc2[mi][ni] = __builtin_amdgcn_mfma_f32_16x16x32_bf16(ah[mi], bl[ni], acc2[mi][ni], 0, 0, 0);
                    acc2[mi][ni] = __builtin_amdgcn_mfma_f32_16x16x32_bf16(al[mi], bh[ni], acc2[mi][ni], 0, 0, 0);
                }
        }
        __syncthreads();
    }

    // ---------- phase 2 epilogue: xbuf0 fp32 + A3 (rnd16(x0)) into LDS ----------
    // A3 layout: [16 kc3][64 rows][8] plain bf16 @ lds[0..8192)
    #pragma unroll
    for (int ni = 0; ni < 2; ++ni) {
        const int colb = w * 32 + ni * 16 + m16;
        const float bb = b2[colb];
        const int kc3 = colb >> 3, k7b = colb & 7;
        #pragma unroll
        for (int mi = 0; mi < 4; ++mi) {
            #pragma unroll
            for (int r = 0; r < 4; ++r) {
                const int rl = mi * 16 + q * 4 + r;
                const float v = acc2[mi][ni][r] + bb;
                Cf[(size_t)(row0 + rl) * DIM + colb] = v;
                lds[kc3 * 512 + rl * 8 + k7b] = (ushort_t)rnd16(v);
            }
        }
    }
    __syncthreads();

    // ---------- phase 3: hb0 = A3 @ l0 (2-term B split) ----------
    // B3 staging: per kb3, 4 kc × 256 cols: B3h @ lds[8192..16384), B3l @ [16384..24576)
    for (int cp = 0; cp < 2; ++cp) {
        f32x4 acc3[4][4] = {};
        for (int kb3 = 0; kb3 < 4; ++kb3) {
            const size_t bo = ((size_t)(kb3 * 4 + w) * 512 + cp * 256) * 8 + lane * 8;
            #pragma unroll
            for (int u = 0; u < 4; ++u) {
                gl_lds16(B3h + bo + u * 512, &lds[8192 + w * 2048 + u * 512]);
                gl_lds16(B3l + bo + u * 512, &lds[16384 + w * 2048 + u * 512]);
            }
            __syncthreads();

            bf16x8 a3[4], b3h[4], b3l[4];
            const int fa3 = (kb3 * 4 + q) * 512 + m16 * 8;
            #pragma unroll
            for (int mi = 0; mi < 4; ++mi)
                a3[mi] = *(const bf16x8*)&lds[fa3 + mi * 128];
            #pragma unroll
            for (int ni = 0; ni < 4; ++ni) {
                const int fb3 = q * 2048 + (w * 64 + ni * 16 + m16) * 8;
                b3h[ni] = *(const bf16x8*)&lds[8192 + fb3];
                b3l[ni] = *(const bf16x8*)&lds[16384 + fb3];
            }
            #pragma unroll
            for (int mi = 0; mi < 4; ++mi)
                #pragma unroll
                for (int ni = 0; ni < 4; ++ni) {
                    acc3[mi][ni] = __builtin_amdgcn_mfma_f32_16x16x32_bf16(a3[mi], b3h[ni], acc3[mi][ni], 0, 0, 0);
                    acc3[mi][ni] = __builtin_amdgcn_mfma_f32_16x16x32_bf16(a3[mi], b3l[ni], acc3[mi][ni], 0, 0, 0);
                }
            __syncthreads();
        }
        // epilogue: hb0 plain bf16 [row][512]
        #pragma unroll
        for (int ni = 0; ni < 4; ++ni) {
            const int col = cp * 256 + w * 64 + ni * 16 + m16;
            #pragma unroll
            for (int mi = 0; mi < 4; ++mi) {
                #pragma unroll
                for (int r = 0; r < 4; ++r) {
                    const int row = row0 + mi * 16 + q * 4 + r;
                    hbout[(size_t)row * 512 + col] = (ushort_t)rnd16(acc3[mi][ni][r]);
                }
            }
        }
    }
}

// ---- x fp32 [N_NODES][F_IN] -> xh/xl bf16 [K8][MP][8], coalesced via LDS tile ----
__global__ __launch_bounds__(256) void conv_a_t_kernel(
    const float* __restrict__ x, ushort_t* __restrict__ xh, ushort_t* __restrict__ xl)
{
    __shared__ float tile[64][68];
    const int tid = threadIdx.x;
    const int r0 = blockIdx.x * 64;
    const int c0 = blockIdx.y * 64;

    #pragma unroll
    for (int it = 0; it < 4; ++it) {
        const int r = (tid >> 4) + it * 16;
        const int c = (tid & 15) * 4;
        const int gr = r0 + r, gc = c0 + c;
        float4 v = {0.f, 0.f, 0.f, 0.f};
        if (gr < N_NODES) {
            if (gc + 3 < F_IN) {
                v = *(const float4*)(x + (size_t)gr * F_IN + gc);
            } else {
                float tmp[4] = {0.f, 0.f, 0.f, 0.f};
                #pragma unroll
                for (int u = 0; u < 4; ++u)
                    if (gc + u < F_IN) tmp[u] = x[(size_t)gr * F_IN + gc + u];
                v.x = tmp[0]; v.y = tmp[1]; v.z = tmp[2]; v.w = tmp[3];
            }
        }
        tile[r][c] = v.x; tile[r][c+1] = v.y; tile[r][c+2] = v.z; tile[r][c+3] = v.w;
    }
    __syncthreads();

    const int k8l = tid >> 5;
    const int k8 = (c0 >> 3) + k8l;
    if (k8 >= 68) return;
    const int rr = (tid & 31) * 2;
    #pragma unroll
    for (int u = 0; u < 2; ++u) {
        const int r = rr + u;
        unsigned int hp[4], lp[4];
        #pragma unroll
        for (int i = 0; i < 4; ++i) {
            const float v0 = tile[r][k8l * 8 + 2 * i];
            const float v1 = tile[r][k8l * 8 + 2 * i + 1];
            hp[i] = (hi16(v1) << 16) | hi16(v0);
            lp[i] = (lo16(v1) << 16) | lo16(v0);
        }
        const size_t p = ((size_t)k8 * MP + r0 + r) * 8;
        *(uint4*)(xh + p) = make_uint4(hp[0], hp[1], hp[2], hp[3]);
        *(uint4*)(xl + p) = make_uint4(lp[0], lp[1], lp[2], lp[3]);
    }
}

// ---- all 4 weights fp32 -> bf16 hi/lo [K8][N][8] in ONE launch ----
#define W1_T (68 * 256 * 8)
#define W2_T (32 * 128 * 8)
#define L_T  (16 * 512 * 8)
__global__ __launch_bounds__(256) void conv_w_all_kernel(
    const float* __restrict__ w1, const float* __restrict__ w2,
    const float* __restrict__ l0, const float* __restrict__ l1,
    ushort_t* __restrict__ w1h, ushort_t* __restrict__ w1l,
    ushort_t* __restrict__ w2h, ushort_t* __restrict__ w2l,
    ushort_t* __restrict__ l0h, ushort_t* __restrict__ l0l,
    ushort_t* __restrict__ l1h, ushort_t* __restrict__ l1l)
{
    int idx = blockIdx.x * 256 + threadIdx.x;
    const float* w; ushort_t *bh, *bl; int K, N, local;
    if (idx < W1_T) { w = w1; bh = w1h; bl = w1l; K = F_IN; N = HIDDEN; local = idx; }
    else if (idx < W1_T + W2_T) { w = w2; bh = w2h; bl = w2l; K = HIDDEN; N = DIM; local = idx - W1_T; }
    else if (idx < W1_T + W2_T + L_T) { w = l0; bh = l0h; bl = l0l; K = DIM; N = 512; local = idx - W1_T - W2_T; }
    else if (idx < W1_T + W2_T + 2 * L_T) { w = l1; bh = l1h; bl = l1l; K = DIM; N = 512; local = idx - W1_T - W2_T - L_T; }
    else return;
    const int j = local & 7;
    const int rem = local >> 3;
    const int n = rem % N;
    const int k = (rem / N) * 8 + j;
    const float v = (k < K) ? w[(size_t)k * N + n] : 0.f;
    bh[local] = (ushort_t)hi16(v);
    bl[local] = (ushort_t)lo16(v);
}

// ---- wa for BOTH layers in one launch ----
__global__ __launch_bounds__(256) void wa2_kernel(
    const float* __restrict__ lin0, const float* __restrict__ lin1,
    const float* __restrict__ atts0, const float* __restrict__ attd0,
    const float* __restrict__ atts1, const float* __restrict__ attd1,
    float* __restrict__ wa_s0, float* __restrict__ wa_d0,
    float* __restrict__ wa_s1, float* __restrict__ wa_d1)
{
    const int wrk = blockIdx.x * 256 + threadIdx.x;
    if (wrk >= 2048) return;
    const int L = wrk >> 10;
    const int sd = (wrk >> 9) & 1;
    const int p = wrk & 511;
    const int h = p >> 7, d = p & 127;
    const float* lin = L ? lin1 : lin0;
    const float* av = L ? (sd ? attd1 : atts1) : (sd ? attd0 : atts0);
    float* out = L ? (sd ? wa_d1 : wa_s1) : (sd ? wa_d0 : wa_s0);
    const float* lp = lin + (size_t)d * (NH * DIM) + h * DIM;
    const float* ap = av + h * DIM;
    float acc = 0.f;
    #pragma unroll 8
    for (int i = 0; i < DIM; ++i) acc += lp[i] * ap[i];
    out[h * DIM + d] = acc;
}

// ---- a_s[n,h], a_d[n,h] from xbuf (fp32 [N][128]) ----
__global__ __launch_bounds__(256) void as_ad_kernel(
    const float* __restrict__ xb, const float* __restrict__ wa_s,
    const float* __restrict__ wa_d, float* __restrict__ a_s, float* __restrict__ a_d)
{
    const int gw = blockIdx.x * 4 + (threadIdx.x >> 6);
    const int lane = threadIdx.x & 63;
    if (gw >= N_NODES * NH) return;
    const int n = gw >> 2, h = gw & 3;
    const float* hp = xb + (size_t)n * DIM;
    float2 hv = *(const float2*)(hp + lane * 2);
    float2 sv = *(const float2*)(wa_s + h * DIM + lane * 2);
    float2 dv = *(const float2*)(wa_d + h * DIM + lane * 2);
    float s = hv.x * sv.x + hv.y * sv.y;
    float d = hv.x * dv.x + hv.y * dv.y;
    #pragma unroll
    for (int off = 32; off > 0; off >>= 1) {
        s += __shfl_down(s, off);
        d += __shfl_down(d, off);
    }
    if (lane == 0) { a_s[n * 4 + h] = s; a_d[n * 4 + h] = d; }
}

// ---- rel attention tables for BOTH layers: blockIdx.x = layer ----
__global__ __launch_bounds__(128) void rel_table2_kernel(
    const float* __restrict__ rel_emb,
    const float* __restrict__ line0, const float* __restrict__ atte0,
    const float* __restrict__ line1, const float* __restrict__ atte1,
    float* __restrict__ table)          // [2][128]
{
    __shared__ float we[32][NH];
    const int L = blockIdx.x;
    const float* line = L ? line1 : line0;
    const float* atte = L ? atte1 : atte0;
    float* tab = table + L * 128;
    const int tid = threadIdx.x;
    const int k = tid >> 2, h = tid & 3;
    float acc = 0.f;
    for (int d = 0; d < DIM; ++d)
        acc += line[(size_t)k * (NH * DIM) + h * DIM + d] * atte[h * DIM + d];
    we[k][h] = acc;
    __syncthreads();
    if (tid < 26 * NH) {
        int r = tid >> 2, hh = tid & 3;
        float t = 0.f;
        for (int kk = 0; kk < 32; ++kk) t += rel_emb[r * 32 + kk] * we[kk][hh];
        tab[r * 4 + hh] = t;
    }
}

// ================= CSR build =================
__global__ __launch_bounds__(256) void hist_kernel(
    const int* __restrict__ dst, int* __restrict__ cnt)
{
    const int e = blockIdx.x * blockDim.x + threadIdx.x;
    if (e >= N_EDGES) return;
    atomicAdd(&cnt[dst[e]], 1);
}

__global__ __launch_bounds__(1024) void scan_kernel(
    const int* __restrict__ cnt, int* __restrict__ ptr, int* __restrict__ ptr_copy)
{
    __shared__ int tsum[1024];
    const int tid = threadIdx.x;
    const int CH = 20;
    const int base = tid * CH;
    int s = 0;
    #pragma unroll
    for (int i = 0; i < CH; ++i) {
        int idx = base + i;
        if (idx < N_NODES) s += cnt[idx];
    }
    tsum[tid] = s;
    __syncthreads();
    for (int off = 1; off < 1024; off <<= 1) {
        int v = (tid >= off) ? tsum[tid - off] : 0;
        __syncthreads();
        tsum[tid] += v;
        __syncthreads();
    }
    int run = (tid == 0) ? 0 : tsum[tid - 1];
    #pragma unroll
    for (int i = 0; i < CH; ++i) {
        int idx = base + i;
        if (idx < N_NODES) {
            ptr[idx] = run;
            ptr_copy[idx] = run;
            run += cnt[idx];
        }
    }
    if (tid == 0) ptr[N_NODES] = N_EDGES;
}

__global__ __launch_bounds__(256) void scatter_kernel(
    const int* __restrict__ src, const int* __restrict__ dst, const int* __restrict__ etype,
    int* __restrict__ ptr_copy, int2* __restrict__ se, int* __restrict__ dcsr)
{
    const int e = blockIdx.x * blockDim.x + threadIdx.x;
    if (e >= N_EDGES) return;
    const int d = dst[e];
    const int pos = atomicAdd(&ptr_copy[d], 1);
    se[pos] = make_int2(src[e], etype[e]);
    dcsr[pos] = d;
}

// ======== per-edge softmax numerator p[j][h], CSR-ordered, fully coalesced ========
__global__ __launch_bounds__(256) void edge_p_kernel(
    const int2* __restrict__ se, const int* __restrict__ dcsr,
    const float* __restrict__ a_s, const float* __restrict__ a_d,
    const float* __restrict__ table, float* __restrict__ p4)
{
    const int j0 = (blockIdx.x * 256 + threadIdx.x) * 2;
    const int2 eA = se[j0], eB = se[j0 + 1];
    const int dA = dcsr[j0], dB = dcsr[j0 + 1];
    const float4 asA = *(const float4*)(a_s + eA.x * 4);
    const float4 asB = *(const float4*)(a_s + eB.x * 4);
    const float4 adA = *(const float4*)(a_d + dA * 4);
    const float4 adB = *(const float4*)(a_d + dB * 4);
    const float4 tA  = *(const float4*)(table + eA.y * 4);
    const float4 tB  = *(const float4*)(table + eB.y * 4);
    float4 oA, oB;
    oA.x = __expf(lrelu02(asA.x + adA.x + tA.x));
    oA.y = __expf(lrelu02(asA.y + adA.y + tA.y));
    oA.z = __expf(lrelu02(asA.z + adA.z + tA.z));
    oA.w = __expf(lrelu02(asA.w + adA.w + tA.w));
    oB.x = __expf(lrelu02(asB.x + adB.x + tB.x));
    oB.y = __expf(lrelu02(asB.y + adB.y + tB.y));
    oB.z = __expf(lrelu02(asB.z + adB.z + tB.z));
    oB.w = __expf(lrelu02(asB.w + adB.w + tB.w));
    *(float4*)(p4 + (size_t)j0 * 4)     = oA;
    *(float4*)(p4 + (size_t)j0 * 4 + 4) = oB;
}

// ======== shared edge-loop body: weighted gather + eh table-sum ========
__device__ __forceinline__ void acc8(float acc[8], float p, const uint4 g)
{
    acc[0] += p * bfl(g.x); acc[1] += p * bfh(g.x);
    acc[2] += p * bfl(g.y); acc[3] += p * bfh(g.y);
    acc[4] += p * bfl(g.z); acc[5] += p * bfh(g.z);
    acc[6] += p * bfl(g.w); acc[7] += p * bfh(g.w);
}

__device__ __forceinline__ void agg_loop(
    int beg, int end, int n, int head, int cbase,
    const int2* __restrict__ se, const float* __restrict__ p4,
    const float* __restrict__ table, const float* __restrict__ a_s, float adh,
    const ushort_t* __restrict__ hb, float acc[8], float& dh)
{
    // self-loop row: issue early so its latency hides under the edge loop
    const uint4 gs = *(const uint4*)(hb + (size_t)n * 512 + cbase);

    float eh = 0.f;
    int j = beg;
    // 8-wide main loop: 8 gathers in flight
    for (; j + 8 <= end; j += 8) {
        int2 E[8];
        #pragma unroll
        for (int u = 0; u < 8; ++u) E[u] = se[j + u];
        const float* pj = p4 + ((size_t)j * 4 + head);
        float p[8];
        #pragma unroll
        for (int u = 0; u < 8; ++u) p[u] = pj[u * 4];
        uint4 g[8];
        #pragma unroll
        for (int u = 0; u < 8; ++u)
            g[u] = *(const uint4*)(hb + (size_t)E[u].x * 512 + cbase);
        float ehs = 0.f, dhs = 0.f;
        #pragma unroll
        for (int u = 0; u < 8; ++u) { ehs += table[E[u].y * 4 + head]; dhs += p[u]; }
        eh += ehs; dh += dhs;
        #pragma unroll
        for (int u = 0; u < 8; ++u) acc8(acc, p[u], g[u]);
    }
    for (; j + 2 <= end; j += 2) {
        const int2 e0 = se[j], e1 = se[j + 1];
        const float* pj = p4 + ((size_t)j * 4 + head);
        const float p0 = pj[0], p1 = pj[4];
        const uint4 g0 = *(const uint4*)(hb + (size_t)e0.x * 512 + cbase);
        const uint4 g1 = *(const uint4*)(hb + (size_t)e1.x * 512 + cbase);
        eh += table[e0.y * 4 + head] + table[e1.y * 4 + head];
        dh += p0 + p1;
        acc8(acc, p0, g0); acc8(acc, p1, g1);
    }
    if (j < end) {
        const int2 e0 = se[j];
        const float p0 = p4[(size_t)j * 4 + head];
        const uint4 g0 = *(const uint4*)(hb + (size_t)e0.x * 512 + cbase);
        eh += table[e0.y * 4 + head];
        dh += p0;
        acc8(acc, p0, g0);
    }
    // self-loop (fill_value='mean')
    const float inv = 1.0f / fmaxf((float)(end - beg), 1.0f);
    const float ps = __expf(lrelu02(a_s[n * 4 + head] + adh + eh * inv));
    dh += ps;
    acc8(acc, ps, gs);
}

// ===== L0 variant: bf16 A-layout out + FUSED next-layer a_s/a_d =====
__global__ __launch_bounds__(256) void node_agg_f_kernel(
    const int* __restrict__ ptr, const int2* __restrict__ se,
    const float* __restrict__ p4, const float* __restrict__ table,
    const float* __restrict__ a_s, const float* __restrict__ a_d,
    const ushort_t* __restrict__ hb,
    const float* __restrict__ bias, ushort_t* __restrict__ oa,
    const float* __restrict__ wa_s2, const float* __restrict__ wa_d2,
    float* __restrict__ a_s2, float* __restrict__ a_d2)
{
    const int n = blockIdx.x * 4 + (threadIdx.x >> 6);
    const int lane = threadIdx.x & 63;
    if (n >= N_NODES) return;
    const int beg = ptr[n], end = ptr[n + 1];
    const int head = lane >> 4;
    const int cbase = lane * 8;
    const float adh = a_d[n * 4 + head];

    float acc[8] = {};
    float dh = 0.f;
    agg_loop(beg, end, n, head, cbase, se, p4, table, a_s, adh, hb, acc, dh);

    const float ih = 0.25f / (dh + 1e-16f);
    float t[8];
    #pragma unroll
    for (int k = 0; k < 8; ++k) {
        t[k] = acc[k] * ih;
        t[k] += __shfl_xor(t[k], 16);
        t[k] += __shfl_xor(t[k], 32);
    }
    if (lane < 16) {
        const float4 b0 = *(const float4*)(bias + cbase);
        const float4 b1 = *(const float4*)(bias + cbase + 4);
        float o[8];
        o[0] = fmaxf(t[0] + b0.x, 0.f); o[1] = fmaxf(t[1] + b0.y, 0.f);
        o[2] = fmaxf(t[2] + b0.z, 0.f); o[3] = fmaxf(t[3] + b0.w, 0.f);
        o[4] = fmaxf(t[4] + b1.x, 0.f); o[5] = fmaxf(t[5] + b1.y, 0.f);
        o[6] = fmaxf(t[6] + b1.z, 0.f); o[7] = fmaxf(t[7] + b1.w, 0.f);
        unsigned int up[4];
        #pragma unroll
        for (int i = 0; i < 4; ++i)
            up[i] = (rnd16(o[2*i+1]) << 16) | rnd16(o[2*i]);
        *(uint4*)(oa + ((size_t)lane * MP + n) * 8) = make_uint4(up[0], up[1], up[2], up[3]);
        // fused next-layer a_s/a_d: per-head 128-dot over the output row
        float pss[4] = {0,0,0,0}, pdd[4] = {0,0,0,0};
        #pragma unroll
        for (int h = 0; h < NH; ++h) {
            const float* ws = wa_s2 + h * DIM + cbase;
            const float* wd = wa_d2 + h * DIM + cbase;
            #pragma unroll
            for (int i = 0; i < 8; ++i) {
                pss[h] += o[i] * ws[i];
                pdd[h] += o[i] * wd[i];
            }
        }
        #pragma unroll
        for (int m = 1; m < 16; m <<= 1) {
            #pragma unroll
            for (int h = 0; h < NH; ++h) {
                pss[h] += __shfl_xor(pss[h], m);
                pdd[h] += __shfl_xor(pdd[h], m);
            }
        }
        if (lane == 0) {
            float4 vs = {pss[0], pss[1], pss[2], pss[3]};
            float4 vd = {pdd[0], pdd[1], pdd[2], pdd[3]};
            *(float4*)(a_s2 + n * 4) = vs;
            *(float4*)(a_d2 + n * 4) = vd;
        }
    }
}

// ===== L1 variant: fp32 out only, no fusion =====
__global__ __launch_bounds__(256) void node_agg_s_kernel(
    const int* __restrict__ ptr, const int2* __restrict__ se,
    const float* __restrict__ p4, const float* __restrict__ table,
    const float* __restrict__ a_s, const float* __restrict__ a_d,
    const ushort_t* __restrict__ hb,
    const float* __restrict__ bias, float* __restrict__ outf)
{
    const int n = blockIdx.x * 4 + (threadIdx.x >> 6);
    const int lane = threadIdx.x & 63;
    if (n >= N_NODES) return;
    const int beg = ptr[n], end = ptr[n + 1];
    const int head = lane >> 4;
    const int cbase = lane * 8;
    const float adh = a_d[n * 4 + head];

    float acc[8] = {};
    float dh = 0.f;
    agg_loop(beg, end, n, head, cbase, se, p4, table, a_s, adh, hb, acc, dh);

    const float ih = 0.25f / (dh + 1e-16f);
    float t[8];
    #pragma unroll
    for (int k = 0; k < 8; ++k) {
        t[k] = acc[k] * ih;
        t[k] += __shfl_xor(t[k], 16);
        t[k] += __shfl_xor(t[k], 32);
    }
    if (lane < 16) {
        const float4 b0 = *(const float4*)(bias + cbase);
        const float4 b1 = *(const float4*)(bias + cbase + 4);
        float4 v0, v1;
        v0.x = fmaxf(t[0] + b0.x, 0.f); v0.y = fmaxf(t[1] + b0.y, 0.f);
        v0.z = fmaxf(t[2] + b0.z, 0.f); v0.w = fmaxf(t[3] + b0.w, 0.f);
        v1.x = fmaxf(t[4] + b1.x, 0.f); v1.y = fmaxf(t[5] + b1.y, 0.f);
        v1.z = fmaxf(t[6] + b1.z, 0.f); v1.w = fmaxf(t[7] + b1.w, 0.f);
        *(float4*)(outf + (size_t)n * DIM + cbase) = v0;
        *(float4*)(outf + (size_t)n * DIM + cbase + 4) = v1;
    }
}

extern "C" void kernel_launch(void* const* d_in, const int* in_sizes, int n_in,
                              void* d_out, int out_size, void* d_ws, size_t ws_size,
                              hipStream_t stream)
{
    const float* x       = (const float*)d_in[0];
    const int*   eidx    = (const int*)d_in[1];
    const int*   etype   = (const int*)d_in[2];
    const float* w1      = (const float*)d_in[3];
    const float* b1      = (const float*)d_in[4];
    const float* w2      = (const float*)d_in[5];
    const float* b2      = (const float*)d_in[6];
    const float* rel_emb = (const float*)d_in[7];
    const float* lin[2]  = {(const float*)d_in[8],  (const float*)d_in[14]};
    const float* line[2] = {(const float*)d_in[9],  (const float*)d_in[15]};
    const float* atts[2] = {(const float*)d_in[10], (const float*)d_in[16]};
    const float* attd[2] = {(const float*)d_in[11], (const float*)d_in[17]};
    const float* atte[2] = {(const float*)d_in[12], (const float*)d_in[18]};
    const float* bias[2] = {(const float*)d_in[13], (const float*)d_in[19]};
    const int* src = eidx;
    const int* dst = eidx + N_EDGES;

    // ---- workspace layout ----
    char* base = (char*)d_ws;
    size_t off = 0;
    auto alloc = [&](size_t bytes) -> void* {
        void* p = base + off;
        off = (off + bytes + 255) & ~(size_t)255;
        return p;
    };
    ushort_t* xh  = (ushort_t*)alloc((size_t)68 * MP * 8 * 2);
    ushort_t* xl  = (ushort_t*)alloc((size_t)68 * MP * 8 * 2);
    ushort_t* hb0 = (ushort_t*)alloc((size_t)MP * 512 * 2);     // DEDICATED hb (no xh alias)
    void* reg1    = alloc((size_t)16 * MP * 8 * 4);             // xbuf0 fp32 | x1a
    ushort_t* w1h = (ushort_t*)alloc(W1_T * 2);
    ushort_t* w1l = (ushort_t*)alloc(W1_T * 2);
    ushort_t* w2h = (ushort_t*)alloc(W2_T * 2);
    ushort_t* w2l = (ushort_t*)alloc(W2_T * 2);
    ushort_t* l0h = (ushort_t*)alloc(L_T * 2);
    ushort_t* l0l = (ushort_t*)alloc(L_T * 2);
    ushort_t* l1h = (ushort_t*)alloc(L_T * 2);
    ushort_t* l1l = (ushort_t*)alloc(L_T * 2);
    float* a_s0  = (float*)alloc(N_NODES * 4 * 4);
    float* a_d0  = (float*)alloc(N_NODES * 4 * 4);
    float* a_s1  = (float*)alloc(N_NODES * 4 * 4);
    float* a_d1  = (float*)alloc(N_NODES * 4 * 4);
    float* table = (float*)alloc(2 * 128 * 4);
    float* wa_s0 = (float*)alloc(512 * 4);
    float* wa_d0 = (float*)alloc(512 * 4);
    float* wa_s1 = (float*)alloc(512 * 4);
    float* wa_d1 = (float*)alloc(512 * 4);
    int*  cnt_i  = (int*)alloc(N_NODES * 4);
    int*  ptr    = (int*)alloc((N_NODES + 4) * 4);
    int*  ptrc   = (int*)alloc(N_NODES * 4);
    int2* se     = (int2*)alloc((size_t)N_EDGES * 8);
    int*  dcsr   = (int*)alloc((size_t)N_EDGES * 4);
    float* p4    = (float*)alloc((size_t)N_EDGES * 4 * 4);

    float* xbuf0 = (float*)reg1;
    ushort_t* x1a = (ushort_t*)reg1;  // node_agg L0 bf16 A-layout out (xbuf0 dead after as_ad)

    const int mtiles = MP / 64;     // 313
    const int ep_grid = N_EDGES / 512;   // 625, exact

    // ---- input conversions (merged launches) ----
    conv_a_t_kernel<<<dim3(MP / 64, 9), 256, 0, stream>>>(x, xh, xl);
    conv_w_all_kernel<<<(W1_T + W2_T + 2 * L_T + 255) / 256, 256, 0, stream>>>(
        w1, w2, lin[0], lin[1], w1h, w1l, w2h, w2l, l0h, l0l, l1h, l1l);
    wa2_kernel<<<8, 256, 0, stream>>>(lin[0], lin[1], atts[0], attd[0], atts[1], attd[1],
                                      wa_s0, wa_d0, wa_s1, wa_d1);
    rel_table2_kernel<<<2, 128, 0, stream>>>(rel_emb, line[0], atte[0], line[1], atte[1], table);

    // ---- CSR build ----
    hipMemsetAsync(cnt_i, 0, N_NODES * sizeof(int), stream);
    hist_kernel<<<(N_EDGES + 255) / 256, 256, 0, stream>>>(dst, cnt_i);
    scan_kernel<<<1, 1024, 0, stream>>>(cnt_i, ptr, ptrc);
    scatter_kernel<<<(N_EDGES + 255) / 256, 256, 0, stream>>>(src, dst, etype, ptrc, se, dcsr);

    // ---- FUSED encoder + L0 GAT lin: x -> x0 (xbuf0) -> hb0 ----
    enc_fused_kernel<<<mtiles, 256, 0, stream>>>(
        xh, xl, w1h, w1l, w2h, w2l, l0h, l0l, b1, b2, xbuf0, hb0);

    // ---- layer 0 ----
    as_ad_kernel<<<N_NODES, 256, 0, stream>>>(xbuf0, wa_s0, wa_d0, a_s0, a_d0);
    edge_p_kernel<<<ep_grid, 256, 0, stream>>>(se, dcsr, a_s0, a_d0, table, p4);
    node_agg_f_kernel<<<(N_NODES + 3) / 4, 256, 0, stream>>>(
        ptr, se, p4, table, a_s0, a_d0, hb0, bias[0], x1a,
        wa_s1, wa_d1, a_s1, a_d1);

    // ---- layer 1 ----
    gemm_mfma_v2<<<dim3((NH * DIM) / 128, mtiles), 256, 0, stream>>>(
        x1a, nullptr, l1h, l1l, nullptr, N_NODES, 16, NH * DIM, 0, nullptr, nullptr, nullptr, hb0, nullptr);
    edge_p_kernel<<<ep_grid, 256, 0, stream>>>(se, dcsr, a_s1, a_d1, table + 128, p4);
    node_agg_s_kernel<<<(N_NODES + 3) / 4, 256, 0, stream>>>(
        ptr, se, p4, table + 128, a_s1, a_d1, hb0, bias[1], (float*)d_out);
}

// Round 7
// 397.922 us; speedup vs baseline: 1.0964x; 1.0137x over previous
//
#include <hip/hip_runtime.h>
#include <math.h>

#define N_NODES 20000
#define MP      20032          // M padded to 64
#define N_EDGES 320000
#define F_IN    518
#define HIDDEN  256
#define DIM     128
#define NH      4

typedef __attribute__((ext_vector_type(8))) short bf16x8;
typedef __attribute__((ext_vector_type(4))) float f32x4;
typedef unsigned short ushort_t;

__device__ __forceinline__ float lrelu02(float x) { return x > 0.f ? x : 0.2f * x; }

__device__ __forceinline__ void gl_lds16(const void* g, void* l) {
    __builtin_amdgcn_global_load_lds(
        (const __attribute__((address_space(1))) unsigned int*)g,
        (__attribute__((address_space(3))) unsigned int*)l, 16, 0, 0);
}

__device__ __forceinline__ unsigned int hi16(float v) { return __float_as_uint(v) >> 16; }
__device__ __forceinline__ unsigned int lo16(float v) {
    unsigned int h = __float_as_uint(v) & 0xFFFF0000u;
    return __float_as_uint(v - __uint_as_float(h)) >> 16;
}
// round-to-nearest-even bf16
__device__ __forceinline__ unsigned int rnd16(float v) {
    unsigned int u = __float_as_uint(v);
    return (u + 0x7FFFu + ((u >> 16) & 1u)) >> 16;
}
__device__ __forceinline__ float bfl(unsigned int u) { return __uint_as_float(u << 16); }
__device__ __forceinline__ float bfh(unsigned int u) { return __uint_as_float(u & 0xFFFF0000u); }

// ====== split-bf16 MFMA GEMM, operands pre-split, k-chunk-major (PROVEN) ======
__global__ __launch_bounds__(256, 4) void gemm_mfma_v2(
    const ushort_t* __restrict__ Ah, const ushort_t* __restrict__ Al,
    const ushort_t* __restrict__ Bh, const ushort_t* __restrict__ Bl,
    const float* __restrict__ bias,
    int M, int K8, int N, int act,
    float* __restrict__ Cf,                                      // fp32 [M][N]
    ushort_t* __restrict__ Ch, ushort_t* __restrict__ Cl,        // split A-layout
    ushort_t* __restrict__ Cb,                                   // plain bf16 [M][N]
    ushort_t* __restrict__ Ca)                                   // plain bf16 A-layout
{
    __shared__ __align__(16) ushort_t lds[12288];
    const int tid = threadIdx.x;
    const int w = tid >> 6, lane = tid & 63;
    const int row0 = blockIdx.y * 64, col0 = blockIdx.x * 128;
    const int nkb = K8 >> 2;
    const int m16 = lane & 15, q = lane >> 4;
    const bool use_al = (Al != nullptr);

    f32x4 acc[4][2] = {};

    for (int kb = 0; kb < nkb; ++kb) {
        const size_t kc = (size_t)(kb * 4 + w);
        const size_t aoff = (kc * MP + row0) * 8 + lane * 8;
        const size_t boff = (kc * N + col0) * 8 + lane * 8;
        gl_lds16(Ah + aoff, &lds[w * 512]);
        if (use_al) gl_lds16(Al + aoff, &lds[2048 + w * 512]);
        gl_lds16(Bh + boff,       &lds[4096 + w * 1024]);
        gl_lds16(Bh + boff + 512, &lds[4096 + w * 1024 + 512]);
        gl_lds16(Bl + boff,       &lds[8192 + w * 1024]);
        gl_lds16(Bl + boff + 512, &lds[8192 + w * 1024 + 512]);
        __syncthreads();

        bf16x8 fah[4], fal[4], fbh[2], fbl[2];
        const int fa = q * 512 + m16 * 8;
        #pragma unroll
        for (int mi = 0; mi < 4; ++mi) {
            fah[mi] = *(const bf16x8*)&lds[fa + mi * 128];
            if (use_al) fal[mi] = *(const bf16x8*)&lds[2048 + fa + mi * 128];
        }
        const int fb = q * 1024 + (w * 32 + m16) * 8;
        #pragma unroll
        for (int ni = 0; ni < 2; ++ni) {
            fbh[ni] = *(const bf16x8*)&lds[4096 + fb + ni * 128];
            fbl[ni] = *(const bf16x8*)&lds[8192 + fb + ni * 128];
        }
        #pragma unroll
        for (int mi = 0; mi < 4; ++mi)
            #pragma unroll
            for (int ni = 0; ni < 2; ++ni) {
                acc[mi][ni] = __builtin_amdgcn_mfma_f32_16x16x32_bf16(fah[mi], fbh[ni], acc[mi][ni], 0, 0, 0);
                acc[mi][ni] = __builtin_amdgcn_mfma_f32_16x16x32_bf16(fah[mi], fbl[ni], acc[mi][ni], 0, 0, 0);
            }
        if (use_al) {
            #pragma unroll
            for (int mi = 0; mi < 4; ++mi)
                #pragma unroll
                for (int ni = 0; ni < 2; ++ni)
                    acc[mi][ni] = __builtin_amdgcn_mfma_f32_16x16x32_bf16(fal[mi], fbh[ni], acc[mi][ni], 0, 0, 0);
        }
        __syncthreads();
    }

    // epilogue: C/D row=(lane>>4)*4+reg, col=lane&15
    #pragma unroll
    for (int ni = 0; ni < 2; ++ni) {
        const int col = col0 + w * 32 + ni * 16 + m16;
        const float bb = bias ? bias[col] : 0.f;
        #pragma unroll
        for (int mi = 0; mi < 4; ++mi) {
            #pragma unroll
            for (int r = 0; r < 4; ++r) {
                const int row = row0 + mi * 16 + q * 4 + r;
                if (row < M) {
                    float v = acc[mi][ni][r] + bb;
                    if (act) v = fmaxf(v, 0.f);
                    if (Cf) Cf[(size_t)row * N + col] = v;
                    if (Cb) Cb[(size_t)row * N + col] = (ushort_t)rnd16(v);
                    const size_t p = (((size_t)(col >> 3)) * MP + row) * 8 + (col & 7);
                    if (Ch) { Ch[p] = (ushort_t)hi16(v); Cl[p] = (ushort_t)lo16(v); }
                    if (Ca) Ca[p] = (ushort_t)rnd16(v);
                }
            }
        }
    }
}

// ====== FUSED node encoder + L0 GAT lin: ======
// Phase 1: h1 = relu(x@w1+b1) in regs (BN=256, A read once).  Phase 2: x0 = h1@w2+b2.
// Phase 3: hb0 = rnd16(x0) @ l0  (2-term split B), written to DEDICATED buffer.
__global__ __launch_bounds__(256, 2) void enc_fused_kernel(
    const ushort_t* __restrict__ Ah, const ushort_t* __restrict__ Al,   // xh, xl [68][MP][8]
    const ushort_t* __restrict__ B1h, const ushort_t* __restrict__ B1l, // w1 [68][256][8]
    const ushort_t* __restrict__ B2h, const ushort_t* __restrict__ B2l, // w2 [32][128][8]
    const ushort_t* __restrict__ B3h, const ushort_t* __restrict__ B3l, // l0 [16][512][8]
    const float* __restrict__ b1, const float* __restrict__ b2,
    float* __restrict__ Cf, ushort_t* __restrict__ hbout)               // xbuf0, hb0
{
    __shared__ __align__(16) ushort_t lds[24576];   // 48 KB
    const int tid = threadIdx.x;
    const int w = tid >> 6, lane = tid & 63;
    const int row0 = blockIdx.x * 64;
    const int m16 = lane & 15, q = lane >> 4;

    // ---------- phase 1 ----------
    // LDS: A1h [4kc][64][8] @0 | A1l @2048 | B1h [4kc][256][8] @4096 | B1l @12288
    f32x4 acc1[4][4] = {};
    for (int kb = 0; kb < 17; ++kb) {
        const size_t kc = (size_t)(kb * 4 + w);
        const size_t aoff = (kc * MP + row0) * 8 + lane * 8;
        const size_t boff = kc * 2048 + lane * 8;
        gl_lds16(Ah + aoff, &lds[w * 512]);
        gl_lds16(Al + aoff, &lds[2048 + w * 512]);
        #pragma unroll
        for (int u = 0; u < 4; ++u) {
            gl_lds16(B1h + boff + u * 512, &lds[4096 + w * 2048 + u * 512]);
            gl_lds16(B1l + boff + u * 512, &lds[12288 + w * 2048 + u * 512]);
        }
        __syncthreads();

        bf16x8 fah[4], fal[4], fbh[4], fbl[4];
        const int fa = q * 512 + m16 * 8;
        #pragma unroll
        for (int mi = 0; mi < 4; ++mi) {
            fah[mi] = *(const bf16x8*)&lds[fa + mi * 128];
            fal[mi] = *(const bf16x8*)&lds[2048 + fa + mi * 128];
        }
        #pragma unroll
        for (int ni = 0; ni < 4; ++ni) {
            const int fb = q * 2048 + (ni * 64 + w * 16 + m16) * 8;
            fbh[ni] = *(const bf16x8*)&lds[4096 + fb];
            fbl[ni] = *(const bf16x8*)&lds[12288 + fb];
        }
        #pragma unroll
        for (int mi = 0; mi < 4; ++mi)
            #pragma unroll
            for (int ni = 0; ni < 4; ++ni) {
                acc1[mi][ni] = __builtin_amdgcn_mfma_f32_16x16x32_bf16(fah[mi], fbh[ni], acc1[mi][ni], 0, 0, 0);
                acc1[mi][ni] = __builtin_amdgcn_mfma_f32_16x16x32_bf16(fah[mi], fbl[ni], acc1[mi][ni], 0, 0, 0);
                acc1[mi][ni] = __builtin_amdgcn_mfma_f32_16x16x32_bf16(fal[mi], fbh[ni], acc1[mi][ni], 0, 0, 0);
            }
        __syncthreads();
    }

    float b1c[4];
    #pragma unroll
    for (int ni = 0; ni < 4; ++ni) b1c[ni] = b1[ni * 64 + w * 16 + m16];

    // ---------- phase 2 ----------
    // LDS: A2h [8kc][64][8] @0 | A2l @4096 | B2h [8kc][128][8] @8192 | B2l @16384
    f32x4 acc2[4][2] = {};
    const int kc2l = w * 2 + (m16 >> 3);
    const int k7 = m16 & 7;
    for (int st = 0; st < 4; ++st) {
        #pragma unroll
        for (int mi = 0; mi < 4; ++mi)
            #pragma unroll
            for (int r = 0; r < 4; ++r) {
                const float v = fmaxf(acc1[mi][st][r] + b1c[st], 0.f);
                const int ad = kc2l * 512 + (mi * 16 + q * 4 + r) * 8 + k7;
                lds[ad] = (ushort_t)hi16(v);
                lds[4096 + ad] = (ushort_t)lo16(v);
            }
        #pragma unroll
        for (int c = 0; c < 2; ++c) {
            const size_t bo = (size_t)(st * 8 + w * 2 + c) * 1024 + lane * 8;
            const int dl = (w * 2 + c) * 1024;
            gl_lds16(B2h + bo,       &lds[8192 + dl]);
            gl_lds16(B2h + bo + 512, &lds[8192 + dl + 512]);
            gl_lds16(B2l + bo,       &lds[16384 + dl]);
            gl_lds16(B2l + bo + 512, &lds[16384 + dl + 512]);
        }
        __syncthreads();

        #pragma unroll
        for (int kb2 = 0; kb2 < 2; ++kb2) {
            bf16x8 ah[4], al[4], bh[2], bl[2];
            const int fa2 = (kb2 * 4 + q) * 512 + m16 * 8;
            #pragma unroll
            for (int mi = 0; mi < 4; ++mi) {
                ah[mi] = *(const bf16x8*)&lds[fa2 + mi * 128];
                al[mi] = *(const bf16x8*)&lds[4096 + fa2 + mi * 128];
            }
            #pragma unroll
            for (int ni = 0; ni < 2; ++ni) {
                const int fb2 = (kb2 * 4 + q) * 1024 + (w * 32 + ni * 16 + m16) * 8;
                bh[ni] = *(const bf16x8*)&lds[8192 + fb2];
                bl[ni] = *(const bf16x8*)&lds[16384 + fb2];
            }
            #pragma unroll
            for (int mi = 0; mi < 4; ++mi)
                #pragma unroll
                for (int ni = 0; ni < 2; ++ni) {
                    acc2[mi][ni] = __builtin_amdgcn_mfma_f32_16x16x32_bf16(ah[mi], bh[ni], acc2[mi][ni], 0, 0, 0);
                    acc2[mi][ni] = __builtin_amdgcn_mfma_f32_16x16x32_bf16(ah[mi], bl[ni], acc2[mi][ni], 0, 0, 0);
                    acc2[mi][ni] = __builtin_amdgcn_mfma_f32_16x16x32_bf16(al[mi], bh[ni], acc2[mi][ni], 0, 0, 0);
                }
        }
        __syncthreads();
    }

    // ---------- phase 2 epilogue: xbuf0 fp32 + A3 (rnd16(x0)) into LDS ----------
    // A3 layout: [16 kc3][64 rows][8] plain bf16 @ lds[0..8192)
    #pragma unroll
    for (int ni = 0; ni < 2; ++ni) {
        const int colb = w * 32 + ni * 16 + m16;
        const float bb = b2[colb];
        const int kc3 = colb >> 3, k7b = colb & 7;
        #pragma unroll
        for (int mi = 0; mi < 4; ++mi) {
            #pragma unroll
            for (int r = 0; r < 4; ++r) {
                const int rl = mi * 16 + q * 4 + r;
                const float v = acc2[mi][ni][r] + bb;
                Cf[(size_t)(row0 + rl) * DIM + colb] = v;
                lds[kc3 * 512 + rl * 8 + k7b] = (ushort_t)rnd16(v);
            }
        }
    }
    __syncthreads();

    // ---------- phase 3: hb0 = A3 @ l0 (2-term B split) ----------
    // B3 staging: per kb3, 4 kc × 256 cols: B3h @ lds[8192..16384), B3l @ [16384..24576)
    for (int cp = 0; cp < 2; ++cp) {
        f32x4 acc3[4][4] = {};
        for (int kb3 = 0; kb3 < 4; ++kb3) {
            const size_t bo = ((size_t)(kb3 * 4 + w) * 512 + cp * 256) * 8 + lane * 8;
            #pragma unroll
            for (int u = 0; u < 4; ++u) {
                gl_lds16(B3h + bo + u * 512, &lds[8192 + w * 2048 + u * 512]);
                gl_lds16(B3l + bo + u * 512, &lds[16384 + w * 2048 + u * 512]);
            }
            __syncthreads();

            bf16x8 a3[4], b3h[4], b3l[4];
            const int fa3 = (kb3 * 4 + q) * 512 + m16 * 8;
            #pragma unroll
            for (int mi = 0; mi < 4; ++mi)
                a3[mi] = *(const bf16x8*)&lds[fa3 + mi * 128];
            #pragma unroll
            for (int ni = 0; ni < 4; ++ni) {
                const int fb3 = q * 2048 + (w * 64 + ni * 16 + m16) * 8;
                b3h[ni] = *(const bf16x8*)&lds[8192 + fb3];
                b3l[ni] = *(const bf16x8*)&lds[16384 + fb3];
            }
            #pragma unroll
            for (int mi = 0; mi < 4; ++mi)
                #pragma unroll
                for (int ni = 0; ni < 4; ++ni) {
                    acc3[mi][ni] = __builtin_amdgcn_mfma_f32_16x16x32_bf16(a3[mi], b3h[ni], acc3[mi][ni], 0, 0, 0);
                    acc3[mi][ni] = __builtin_amdgcn_mfma_f32_16x16x32_bf16(a3[mi], b3l[ni], acc3[mi][ni], 0, 0, 0);
                }
            __syncthreads();
        }
        // epilogue: hb0 plain bf16 [row][512]
        #pragma unroll
        for (int ni = 0; ni < 4; ++ni) {
            const int col = cp * 256 + w * 64 + ni * 16 + m16;
            #pragma unroll
            for (int mi = 0; mi < 4; ++mi) {
                #pragma unroll
                for (int r = 0; r < 4; ++r) {
                    const int row = row0 + mi * 16 + q * 4 + r;
                    hbout[(size_t)row * 512 + col] = (ushort_t)rnd16(acc3[mi][ni][r]);
                }
            }
        }
    }
}

// ---- x fp32 [N_NODES][F_IN] -> xh/xl bf16 [K8][MP][8], coalesced via LDS tile ----
__global__ __launch_bounds__(256) void conv_a_t_kernel(
    const float* __restrict__ x, ushort_t* __restrict__ xh, ushort_t* __restrict__ xl)
{
    __shared__ float tile[64][68];
    const int tid = threadIdx.x;
    const int r0 = blockIdx.x * 64;
    const int c0 = blockIdx.y * 64;

    #pragma unroll
    for (int it = 0; it < 4; ++it) {
        const int r = (tid >> 4) + it * 16;
        const int c = (tid & 15) * 4;
        const int gr = r0 + r, gc = c0 + c;
        float4 v = {0.f, 0.f, 0.f, 0.f};
        if (gr < N_NODES) {
            if (gc + 3 < F_IN) {
                v = *(const float4*)(x + (size_t)gr * F_IN + gc);
            } else {
                float tmp[4] = {0.f, 0.f, 0.f, 0.f};
                #pragma unroll
                for (int u = 0; u < 4; ++u)
                    if (gc + u < F_IN) tmp[u] = x[(size_t)gr * F_IN + gc + u];
                v.x = tmp[0]; v.y = tmp[1]; v.z = tmp[2]; v.w = tmp[3];
            }
        }
        tile[r][c] = v.x; tile[r][c+1] = v.y; tile[r][c+2] = v.z; tile[r][c+3] = v.w;
    }
    __syncthreads();

    const int k8l = tid >> 5;
    const int k8 = (c0 >> 3) + k8l;
    if (k8 >= 68) return;
    const int rr = (tid & 31) * 2;
    #pragma unroll
    for (int u = 0; u < 2; ++u) {
        const int r = rr + u;
        unsigned int hp[4], lp[4];
        #pragma unroll
        for (int i = 0; i < 4; ++i) {
            const float v0 = tile[r][k8l * 8 + 2 * i];
            const float v1 = tile[r][k8l * 8 + 2 * i + 1];
            hp[i] = (hi16(v1) << 16) | hi16(v0);
            lp[i] = (lo16(v1) << 16) | lo16(v0);
        }
        const size_t p = ((size_t)k8 * MP + r0 + r) * 8;
        *(uint4*)(xh + p) = make_uint4(hp[0], hp[1], hp[2], hp[3]);
        *(uint4*)(xl + p) = make_uint4(lp[0], lp[1], lp[2], lp[3]);
    }
}

// ---- all 4 weights fp32 -> bf16 hi/lo [K8][N][8] in ONE launch ----
#define W1_T (68 * 256 * 8)
#define W2_T (32 * 128 * 8)
#define L_T  (16 * 512 * 8)
__global__ __launch_bounds__(256) void conv_w_all_kernel(
    const float* __restrict__ w1, const float* __restrict__ w2,
    const float* __restrict__ l0, const float* __restrict__ l1,
    ushort_t* __restrict__ w1h, ushort_t* __restrict__ w1l,
    ushort_t* __restrict__ w2h, ushort_t* __restrict__ w2l,
    ushort_t* __restrict__ l0h, ushort_t* __restrict__ l0l,
    ushort_t* __restrict__ l1h, ushort_t* __restrict__ l1l)
{
    int idx = blockIdx.x * 256 + threadIdx.x;
    const float* w; ushort_t *bh, *bl; int K, N, local;
    if (idx < W1_T) { w = w1; bh = w1h; bl = w1l; K = F_IN; N = HIDDEN; local = idx; }
    else if (idx < W1_T + W2_T) { w = w2; bh = w2h; bl = w2l; K = HIDDEN; N = DIM; local = idx - W1_T; }
    else if (idx < W1_T + W2_T + L_T) { w = l0; bh = l0h; bl = l0l; K = DIM; N = 512; local = idx - W1_T - W2_T; }
    else if (idx < W1_T + W2_T + 2 * L_T) { w = l1; bh = l1h; bl = l1l; K = DIM; N = 512; local = idx - W1_T - W2_T - L_T; }
    else return;
    const int j = local & 7;
    const int rem = local >> 3;
    const int n = rem % N;
    const int k = (rem / N) * 8 + j;
    const float v = (k < K) ? w[(size_t)k * N + n] : 0.f;
    bh[local] = (ushort_t)hi16(v);
    bl[local] = (ushort_t)lo16(v);
}

// ---- wa for BOTH layers in one launch ----
__global__ __launch_bounds__(256) void wa2_kernel(
    const float* __restrict__ lin0, const float* __restrict__ lin1,
    const float* __restrict__ atts0, const float* __restrict__ attd0,
    const float* __restrict__ atts1, const float* __restrict__ attd1,
    float* __restrict__ wa_s0, float* __restrict__ wa_d0,
    float* __restrict__ wa_s1, float* __restrict__ wa_d1)
{
    const int wrk = blockIdx.x * 256 + threadIdx.x;
    if (wrk >= 2048) return;
    const int L = wrk >> 10;
    const int sd = (wrk >> 9) & 1;
    const int p = wrk & 511;
    const int h = p >> 7, d = p & 127;
    const float* lin = L ? lin1 : lin0;
    const float* av = L ? (sd ? attd1 : atts1) : (sd ? attd0 : atts0);
    float* out = L ? (sd ? wa_d1 : wa_s1) : (sd ? wa_d0 : wa_s0);
    const float* lp = lin + (size_t)d * (NH * DIM) + h * DIM;
    const float* ap = av + h * DIM;
    float acc = 0.f;
    #pragma unroll 8
    for (int i = 0; i < DIM; ++i) acc += lp[i] * ap[i];
    out[h * DIM + d] = acc;
}

// ---- a_s[n,h], a_d[n,h] from xbuf (fp32 [N][128]) ----
__global__ __launch_bounds__(256) void as_ad_kernel(
    const float* __restrict__ xb, const float* __restrict__ wa_s,
    const float* __restrict__ wa_d, float* __restrict__ a_s, float* __restrict__ a_d)
{
    const int gw = blockIdx.x * 4 + (threadIdx.x >> 6);
    const int lane = threadIdx.x & 63;
    if (gw >= N_NODES * NH) return;
    const int n = gw >> 2, h = gw & 3;
    const float* hp = xb + (size_t)n * DIM;
    float2 hv = *(const float2*)(hp + lane * 2);
    float2 sv = *(const float2*)(wa_s + h * DIM + lane * 2);
    float2 dv = *(const float2*)(wa_d + h * DIM + lane * 2);
    float s = hv.x * sv.x + hv.y * sv.y;
    float d = hv.x * dv.x + hv.y * dv.y;
    #pragma unroll
    for (int off = 32; off > 0; off >>= 1) {
        s += __shfl_down(s, off);
        d += __shfl_down(d, off);
    }
    if (lane == 0) { a_s[n * 4 + h] = s; a_d[n * 4 + h] = d; }
}

// ---- rel attention tables for BOTH layers: blockIdx.x = layer ----
__global__ __launch_bounds__(128) void rel_table2_kernel(
    const float* __restrict__ rel_emb,
    const float* __restrict__ line0, const float* __restrict__ atte0,
    const float* __restrict__ line1, const float* __restrict__ atte1,
    float* __restrict__ table)          // [2][128]
{
    __shared__ float we[32][NH];
    const int L = blockIdx.x;
    const float* line = L ? line1 : line0;
    const float* atte = L ? atte1 : atte0;
    float* tab = table + L * 128;
    const int tid = threadIdx.x;
    const int k = tid >> 2, h = tid & 3;
    float acc = 0.f;
    for (int d = 0; d < DIM; ++d)
        acc += line[(size_t)k * (NH * DIM) + h * DIM + d] * atte[h * DIM + d];
    we[k][h] = acc;
    __syncthreads();
    if (tid < 26 * NH) {
        int r = tid >> 2, hh = tid & 3;
        float t = 0.f;
        for (int kk = 0; kk < 32; ++kk) t += rel_emb[r * 32 + kk] * we[kk][hh];
        tab[r * 4 + hh] = t;
    }
}

// ================= CSR build =================
__global__ __launch_bounds__(256) void hist_kernel(
    const int* __restrict__ dst, int* __restrict__ cnt)
{
    const int e = blockIdx.x * blockDim.x + threadIdx.x;
    if (e >= N_EDGES) return;
    atomicAdd(&cnt[dst[e]], 1);
}

__global__ __launch_bounds__(1024) void scan_kernel(
    const int* __restrict__ cnt, int* __restrict__ ptr, int* __restrict__ ptr_copy)
{
    __shared__ int tsum[1024];
    const int tid = threadIdx.x;
    const int CH = 20;
    const int base = tid * CH;
    int s = 0;
    #pragma unroll
    for (int i = 0; i < CH; ++i) {
        int idx = base + i;
        if (idx < N_NODES) s += cnt[idx];
    }
    tsum[tid] = s;
    __syncthreads();
    for (int off = 1; off < 1024; off <<= 1) {
        int v = (tid >= off) ? tsum[tid - off] : 0;
        __syncthreads();
        tsum[tid] += v;
        __syncthreads();
    }
    int run = (tid == 0) ? 0 : tsum[tid - 1];
    #pragma unroll
    for (int i = 0; i < CH; ++i) {
        int idx = base + i;
        if (idx < N_NODES) {
            ptr[idx] = run;
            ptr_copy[idx] = run;
            run += cnt[idx];
        }
    }
    if (tid == 0) ptr[N_NODES] = N_EDGES;
}

__global__ __launch_bounds__(256) void scatter_kernel(
    const int* __restrict__ src, const int* __restrict__ dst, const int* __restrict__ etype,
    int* __restrict__ ptr_copy, int2* __restrict__ se, int* __restrict__ dcsr)
{
    const int e = blockIdx.x * blockDim.x + threadIdx.x;
    if (e >= N_EDGES) return;
    const int d = dst[e];
    const int pos = atomicAdd(&ptr_copy[d], 1);
    se[pos] = make_int2(src[e], etype[e]);
    dcsr[pos] = d;
}

// ======== per-edge softmax numerator p[j][h], CSR-ordered, fully coalesced ========
__global__ __launch_bounds__(256) void edge_p_kernel(
    const int2* __restrict__ se, const int* __restrict__ dcsr,
    const float* __restrict__ a_s, const float* __restrict__ a_d,
    const float* __restrict__ table, float* __restrict__ p4)
{
    const int j0 = (blockIdx.x * 256 + threadIdx.x) * 2;
    const int2 eA = se[j0], eB = se[j0 + 1];
    const int dA = dcsr[j0], dB = dcsr[j0 + 1];
    const float4 asA = *(const float4*)(a_s + eA.x * 4);
    const float4 asB = *(const float4*)(a_s + eB.x * 4);
    const float4 adA = *(const float4*)(a_d + dA * 4);
    const float4 adB = *(const float4*)(a_d + dB * 4);
    const float4 tA  = *(const float4*)(table + eA.y * 4);
    const float4 tB  = *(const float4*)(table + eB.y * 4);
    float4 oA, oB;
    oA.x = __expf(lrelu02(asA.x + adA.x + tA.x));
    oA.y = __expf(lrelu02(asA.y + adA.y + tA.y));
    oA.z = __expf(lrelu02(asA.z + adA.z + tA.z));
    oA.w = __expf(lrelu02(asA.w + adA.w + tA.w));
    oB.x = __expf(lrelu02(asB.x + adB.x + tB.x));
    oB.y = __expf(lrelu02(asB.y + adB.y + tB.y));
    oB.z = __expf(lrelu02(asB.z + adB.z + tB.z));
    oB.w = __expf(lrelu02(asB.w + adB.w + tB.w));
    *(float4*)(p4 + (size_t)j0 * 4)     = oA;
    *(float4*)(p4 + (size_t)j0 * 4 + 4) = oB;
}

// ======== shared edge-loop body: weighted gather + eh table-sum (PROVEN 4-wide) ========
__device__ __forceinline__ void acc8(float acc[8], float p, const uint4 g)
{
    acc[0] += p * bfl(g.x); acc[1] += p * bfh(g.x);
    acc[2] += p * bfl(g.y); acc[3] += p * bfh(g.y);
    acc[4] += p * bfl(g.z); acc[5] += p * bfh(g.z);
    acc[6] += p * bfl(g.w); acc[7] += p * bfh(g.w);
}

__device__ __forceinline__ void agg_loop(
    int beg, int end, int n, int head, int cbase,
    const int2* __restrict__ se, const float* __restrict__ p4,
    const float* __restrict__ table, const float* __restrict__ a_s, float adh,
    const ushort_t* __restrict__ hb, float acc[8], float& dh)
{
    // self-loop row: issue early so its latency hides under the edge loop
    const uint4 gs = *(const uint4*)(hb + (size_t)n * 512 + cbase);

    float eh = 0.f;
    int j = beg;
    for (; j + 4 <= end; j += 4) {
        const int2 e0 = se[j],     e1 = se[j + 1];
        const int2 e2 = se[j + 2], e3 = se[j + 3];
        const float* pj = p4 + ((size_t)j * 4 + head);
        const float p0 = pj[0], p1 = pj[4], p2 = pj[8], p3 = pj[12];
        const uint4 g0 = *(const uint4*)(hb + (size_t)e0.x * 512 + cbase);
        const uint4 g1 = *(const uint4*)(hb + (size_t)e1.x * 512 + cbase);
        const uint4 g2 = *(const uint4*)(hb + (size_t)e2.x * 512 + cbase);
        const uint4 g3 = *(const uint4*)(hb + (size_t)e3.x * 512 + cbase);
        eh += (table[e0.y * 4 + head] + table[e1.y * 4 + head])
            + (table[e2.y * 4 + head] + table[e3.y * 4 + head]);
        dh += (p0 + p1) + (p2 + p3);
        acc8(acc, p0, g0); acc8(acc, p1, g1);
        acc8(acc, p2, g2); acc8(acc, p3, g3);
    }
    for (; j + 2 <= end; j += 2) {
        const int2 e0 = se[j], e1 = se[j + 1];
        const float* pj = p4 + ((size_t)j * 4 + head);
        const float p0 = pj[0], p1 = pj[4];
        const uint4 g0 = *(const uint4*)(hb + (size_t)e0.x * 512 + cbase);
        const uint4 g1 = *(const uint4*)(hb + (size_t)e1.x * 512 + cbase);
        eh += table[e0.y * 4 + head] + table[e1.y * 4 + head];
        dh += p0 + p1;
        acc8(acc, p0, g0); acc8(acc, p1, g1);
    }
    if (j < end) {
        const int2 e0 = se[j];
        const float p0 = p4[(size_t)j * 4 + head];
        const uint4 g0 = *(const uint4*)(hb + (size_t)e0.x * 512 + cbase);
        eh += table[e0.y * 4 + head];
        dh += p0;
        acc8(acc, p0, g0);
    }
    // self-loop (fill_value='mean')
    const float inv = 1.0f / fmaxf((float)(end - beg), 1.0f);
    const float ps = __expf(lrelu02(a_s[n * 4 + head] + adh + eh * inv));
    dh += ps;
    acc8(acc, ps, gs);
}

// ===== L0 variant: 1-wave blocks (degree-imbalance repacking) + fused next a_s/a_d =====
__global__ __launch_bounds__(64) void node_agg_f_kernel(
    const int* __restrict__ ptr, const int2* __restrict__ se,
    const float* __restrict__ p4, const float* __restrict__ table,
    const float* __restrict__ a_s, const float* __restrict__ a_d,
    const ushort_t* __restrict__ hb,
    const float* __restrict__ bias, ushort_t* __restrict__ oa,
    const float* __restrict__ wa_s2, const float* __restrict__ wa_d2,
    float* __restrict__ a_s2, float* __restrict__ a_d2)
{
    const int n = blockIdx.x;
    const int lane = threadIdx.x;
    const int beg = ptr[n], end = ptr[n + 1];
    const int head = lane >> 4;
    const int cbase = lane * 8;
    const float adh = a_d[n * 4 + head];

    float acc[8] = {};
    float dh = 0.f;
    agg_loop(beg, end, n, head, cbase, se, p4, table, a_s, adh, hb, acc, dh);

    const float ih = 0.25f / (dh + 1e-16f);
    float t[8];
    #pragma unroll
    for (int k = 0; k < 8; ++k) {
        t[k] = acc[k] * ih;
        t[k] += __shfl_xor(t[k], 16);
        t[k] += __shfl_xor(t[k], 32);
    }
    if (lane < 16) {
        const float4 b0 = *(const float4*)(bias + cbase);
        const float4 b1 = *(const float4*)(bias + cbase + 4);
        float o[8];
        o[0] = fmaxf(t[0] + b0.x, 0.f); o[1] = fmaxf(t[1] + b0.y, 0.f);
        o[2] = fmaxf(t[2] + b0.z, 0.f); o[3] = fmaxf(t[3] + b0.w, 0.f);
        o[4] = fmaxf(t[4] + b1.x, 0.f); o[5] = fmaxf(t[5] + b1.y, 0.f);
        o[6] = fmaxf(t[6] + b1.z, 0.f); o[7] = fmaxf(t[7] + b1.w, 0.f);
        unsigned int up[4];
        #pragma unroll
        for (int i = 0; i < 4; ++i)
            up[i] = (rnd16(o[2*i+1]) << 16) | rnd16(o[2*i]);
        *(uint4*)(oa + ((size_t)lane * MP + n) * 8) = make_uint4(up[0], up[1], up[2], up[3]);
        // fused next-layer a_s/a_d: per-head 128-dot over the output row
        float pss[4] = {0,0,0,0}, pdd[4] = {0,0,0,0};
        #pragma unroll
        for (int h = 0; h < NH; ++h) {
            const float* ws = wa_s2 + h * DIM + cbase;
            const float* wd = wa_d2 + h * DIM + cbase;
            #pragma unroll
            for (int i = 0; i < 8; ++i) {
                pss[h] += o[i] * ws[i];
                pdd[h] += o[i] * wd[i];
            }
        }
        #pragma unroll
        for (int m = 1; m < 16; m <<= 1) {
            #pragma unroll
            for (int h = 0; h < NH; ++h) {
                pss[h] += __shfl_xor(pss[h], m);
                pdd[h] += __shfl_xor(pdd[h], m);
            }
        }
        if (lane == 0) {
            float4 vs = {pss[0], pss[1], pss[2], pss[3]};
            float4 vd = {pdd[0], pdd[1], pdd[2], pdd[3]};
            *(float4*)(a_s2 + n * 4) = vs;
            *(float4*)(a_d2 + n * 4) = vd;
        }
    }
}

// ===== L1 variant: 1-wave blocks, fp32 out only =====
__global__ __launch_bounds__(64) void node_agg_s_kernel(
    const int* __restrict__ ptr, const int2* __restrict__ se,
    const float* __restrict__ p4, const float* __restrict__ table,
    const float* __restrict__ a_s, const float* __restrict__ a_d,
    const ushort_t* __restrict__ hb,
    const float* __restrict__ bias, float* __restrict__ outf)
{
    const int n = blockIdx.x;
    const int lane = threadIdx.x;
    const int beg = ptr[n], end = ptr[n + 1];
    const int head = lane >> 4;
    const int cbase = lane * 8;
    const float adh = a_d[n * 4 + head];

    float acc[8] = {};
    float dh = 0.f;
    agg_loop(beg, end, n, head, cbase, se, p4, table, a_s, adh, hb, acc, dh);

    const float ih = 0.25f / (dh + 1e-16f);
    float t[8];
    #pragma unroll
    for (int k = 0; k < 8; ++k) {
        t[k] = acc[k] * ih;
        t[k] += __shfl_xor(t[k], 16);
        t[k] += __shfl_xor(t[k], 32);
    }
    if (lane < 16) {
        const float4 b0 = *(const float4*)(bias + cbase);
        const float4 b1 = *(const float4*)(bias + cbase + 4);
        float4 v0, v1;
        v0.x = fmaxf(t[0] + b0.x, 0.f); v0.y = fmaxf(t[1] + b0.y, 0.f);
        v0.z = fmaxf(t[2] + b0.z, 0.f); v0.w = fmaxf(t[3] + b0.w, 0.f);
        v1.x = fmaxf(t[4] + b1.x, 0.f); v1.y = fmaxf(t[5] + b1.y, 0.f);
        v1.z = fmaxf(t[6] + b1.z, 0.f); v1.w = fmaxf(t[7] + b1.w, 0.f);
        *(float4*)(outf + (size_t)n * DIM + cbase) = v0;
        *(float4*)(outf + (size_t)n * DIM + cbase + 4) = v1;
    }
}

extern "C" void kernel_launch(void* const* d_in, const int* in_sizes, int n_in,
                              void* d_out, int out_size, void* d_ws, size_t ws_size,
                              hipStream_t stream)
{
    const float* x       = (const float*)d_in[0];
    const int*   eidx    = (const int*)d_in[1];
    const int*   etype   = (const int*)d_in[2];
    const float* w1      = (const float*)d_in[3];
    const float* b1      = (const float*)d_in[4];
    const float* w2      = (const float*)d_in[5];
    const float* b2      = (const float*)d_in[6];
    const float* rel_emb = (const float*)d_in[7];
    const float* lin[2]  = {(const float*)d_in[8],  (const float*)d_in[14]};
    const float* line[2] = {(const float*)d_in[9],  (const float*)d_in[15]};
    const float* atts[2] = {(const float*)d_in[10], (const float*)d_in[16]};
    const float* attd[2] = {(const float*)d_in[11], (const float*)d_in[17]};
    const float* atte[2] = {(const float*)d_in[12], (const float*)d_in[18]};
    const float* bias[2] = {(const float*)d_in[13], (const float*)d_in[19]};
    const int* src = eidx;
    const int* dst = eidx + N_EDGES;

    // ---- workspace layout ----
    char* base = (char*)d_ws;
    size_t off = 0;
    auto alloc = [&](size_t bytes) -> void* {
        void* p = base + off;
        off = (off + bytes + 255) & ~(size_t)255;
        return p;
    };
    ushort_t* xh  = (ushort_t*)alloc((size_t)68 * MP * 8 * 2);
    ushort_t* xl  = (ushort_t*)alloc((size_t)68 * MP * 8 * 2);
    ushort_t* hb0 = (ushort_t*)alloc((size_t)MP * 512 * 2);     // DEDICATED hb (no xh alias)
    void* reg1    = alloc((size_t)16 * MP * 8 * 4);             // xbuf0 fp32 | x1a
    ushort_t* w1h = (ushort_t*)alloc(W1_T * 2);
    ushort_t* w1l = (ushort_t*)alloc(W1_T * 2);
    ushort_t* w2h = (ushort_t*)alloc(W2_T * 2);
    ushort_t* w2l = (ushort_t*)alloc(W2_T * 2);
    ushort_t* l0h = (ushort_t*)alloc(L_T * 2);
    ushort_t* l0l = (ushort_t*)alloc(L_T * 2);
    ushort_t* l1h = (ushort_t*)alloc(L_T * 2);
    ushort_t* l1l = (ushort_t*)alloc(L_T * 2);
    float* a_s0  = (float*)alloc(N_NODES * 4 * 4);
    float* a_d0  = (float*)alloc(N_NODES * 4 * 4);
    float* a_s1  = (float*)alloc(N_NODES * 4 * 4);
    float* a_d1  = (float*)alloc(N_NODES * 4 * 4);
    float* table = (float*)alloc(2 * 128 * 4);
    float* wa_s0 = (float*)alloc(512 * 4);
    float* wa_d0 = (float*)alloc(512 * 4);
    float* wa_s1 = (float*)alloc(512 * 4);
    float* wa_d1 = (float*)alloc(512 * 4);
    int*  cnt_i  = (int*)alloc(N_NODES * 4);
    int*  ptr    = (int*)alloc((N_NODES + 4) * 4);
    int*  ptrc   = (int*)alloc(N_NODES * 4);
    int2* se     = (int2*)alloc((size_t)N_EDGES * 8);
    int*  dcsr   = (int*)alloc((size_t)N_EDGES * 4);
    float* p4    = (float*)alloc((size_t)N_EDGES * 4 * 4);

    float* xbuf0 = (float*)reg1;
    ushort_t* x1a = (ushort_t*)reg1;  // node_agg L0 bf16 A-layout out (xbuf0 dead after as_ad)

    const int mtiles = MP / 64;     // 313
    const int ep_grid = N_EDGES / 512;   // 625, exact

    // ---- input conversions (merged launches) ----
    conv_a_t_kernel<<<dim3(MP / 64, 9), 256, 0, stream>>>(x, xh, xl);
    conv_w_all_kernel<<<(W1_T + W2_T + 2 * L_T + 255) / 256, 256, 0, stream>>>(
        w1, w2, lin[0], lin[1], w1h, w1l, w2h, w2l, l0h, l0l, l1h, l1l);
    wa2_kernel<<<8, 256, 0, stream>>>(lin[0], lin[1], atts[0], attd[0], atts[1], attd[1],
                                      wa_s0, wa_d0, wa_s1, wa_d1);
    rel_table2_kernel<<<2, 128, 0, stream>>>(rel_emb, line[0], atte[0], line[1], atte[1], table);

    // ---- CSR build ----
    hipMemsetAsync(cnt_i, 0, N_NODES * sizeof(int), stream);
    hist_kernel<<<(N_EDGES + 255) / 256, 256, 0, stream>>>(dst, cnt_i);
    scan_kernel<<<1, 1024, 0, stream>>>(cnt_i, ptr, ptrc);
    scatter_kernel<<<(N_EDGES + 255) / 256, 256, 0, stream>>>(src, dst, etype, ptrc, se, dcsr);

    // ---- FUSED encoder + L0 GAT lin: x -> x0 (xbuf0) -> hb0 ----
    enc_fused_kernel<<<mtiles, 256, 0, stream>>>(
        xh, xl, w1h, w1l, w2h, w2l, l0h, l0l, b1, b2, xbuf0, hb0);

    // ---- layer 0 ----
    as_ad_kernel<<<N_NODES, 256, 0, stream>>>(xbuf0, wa_s0, wa_d0, a_s0, a_d0);
    edge_p_kernel<<<ep_grid, 256, 0, stream>>>(se, dcsr, a_s0, a_d0, table, p4);
    node_agg_f_kernel<<<N_NODES, 64, 0, stream>>>(
        ptr, se, p4, table, a_s0, a_d0, hb0, bias[0], x1a,
        wa_s1, wa_d1, a_s1, a_d1);

    // ---- layer 1 ----
    gemm_mfma_v2<<<dim3((NH * DIM) / 128, mtiles), 256, 0, stream>>>(
        x1a, nullptr, l1h, l1l, nullptr, N_NODES, 16, NH * DIM, 0, nullptr, nullptr, nullptr, hb0, nullptr);
    edge_p_kernel<<<ep_grid, 256, 0, stream>>>(se, dcsr, a_s1, a_d1, table + 128, p4);
    node_agg_s_kernel<<<N_NODES, 64, 0, stream>>>(
        ptr, se, p4, table + 128, a_s1, a_d1, hb0, bias[1], (float*)d_out);
}